// Round 1
// baseline (583.296 us; speedup 1.0000x reference)
//
#include <hip/hip_runtime.h>
#include <hip/hip_bf16.h>
#include <math.h>

typedef __attribute__((ext_vector_type(8))) short short8;
typedef __attribute__((ext_vector_type(4))) float floatx4;
using bf16 = __hip_bfloat16;

#define DEVI __device__ __forceinline__

DEVI floatx4 fzero4() { floatx4 z; z[0]=0.f; z[1]=0.f; z[2]=0.f; z[3]=0.f; return z; }

DEVI unsigned short f2b(float x) {
  union { bf16 h; unsigned short u; } c;
  c.h = __float2bfloat16(x);
  return c.u;
}

// ---------------- cast f32 -> bf16 (8 elems/thread, vectorized) ----------------
__global__ __launch_bounds__(256) void k_cast(const float* __restrict__ in,
                                              bf16* __restrict__ out, int n) {
  int i = (blockIdx.x * 256 + threadIdx.x) * 8;
  if (i >= n) return;
  float4 a = *(const float4*)(in + i);
  float4 b = *(const float4*)(in + i + 4);
  short8 v;
  v[0] = (short)f2b(a.x); v[1] = (short)f2b(a.y);
  v[2] = (short)f2b(a.z); v[3] = (short)f2b(a.w);
  v[4] = (short)f2b(b.x); v[5] = (short)f2b(b.y);
  v[6] = (short)f2b(b.z); v[7] = (short)f2b(b.w);
  *(short8*)(out + i) = v;
}

// ---------------- transpose + cast: out[c][r] = in[r][c] ----------------
__global__ __launch_bounds__(256) void k_transpose(const float* __restrict__ in,
                                                   bf16* __restrict__ out,
                                                   int R, int C) {
  __shared__ float tile[32][33];
  int x = blockIdx.x * 32 + threadIdx.x;
  for (int i = threadIdx.y; i < 32; i += 8) {
    int y = blockIdx.y * 32 + i;
    tile[i][threadIdx.x] = (y < R && x < C) ? in[(size_t)y * C + x] : 0.f;
  }
  __syncthreads();
  int ox = blockIdx.y * 32 + threadIdx.x;   // output col = input row
  for (int i = threadIdx.y; i < 32; i += 8) {
    int oy = blockIdx.x * 32 + i;           // output row = input col
    if (oy < C && ox < R) out[(size_t)oy * R + ox] = __float2bfloat16(tile[threadIdx.x][i]);
  }
}

// ---------------- GEMM: C = A[M,K] @ Bt[N,K]^T + bias ----------------
// 128x128 tile, BK=32, 4 waves (2x2), each wave 64x64 via 4x4 16x16x32 MFMA frags.
// MODE 0: epilogue scatters to Q (scaled 1/8), K, V-transposed (bf16).
// MODE 1: epilogue writes f32 out.
template<int MODE>
__global__ __launch_bounds__(256) void k_gemm(
    const bf16* __restrict__ A, const bf16* __restrict__ Bt,
    const float* __restrict__ bias,
    bf16* __restrict__ Qo, bf16* __restrict__ Ko, bf16* __restrict__ Vo,
    float* __restrict__ Fo, int M, int N, int Kd) {
  __shared__ bf16 sA[128 * 32];
  __shared__ bf16 sB[128 * 32];
  const int tid = threadIdx.x;
  const int w = tid >> 6, l = tid & 63;
  const int lg = l >> 4, li = l & 15;
  const int wr = w >> 1, wc = w & 1;
  const int m0 = blockIdx.y * 128, n0 = blockIdx.x * 128;

  // staging: tile is 128 rows x 32 k of bf16 = 8KB; 512 slots of 16B; thread does
  // slots tid and tid+256.  slot s -> row s>>2, k-offset (s&3)*8.
  const int r0 = tid >> 2, ko0 = (tid & 3) * 8;
  const bf16* pa0 = A + (size_t)(m0 + r0) * Kd + ko0;
  const bf16* pa1 = A + (size_t)(m0 + 64 + r0) * Kd + ko0;
  const bf16* pb0 = Bt + (size_t)(n0 + r0) * Kd + ko0;
  const bf16* pb1 = Bt + (size_t)(n0 + 64 + r0) * Kd + ko0;

  floatx4 acc[4][4];
#pragma unroll
  for (int i = 0; i < 4; ++i)
#pragma unroll
    for (int j = 0; j < 4; ++j) acc[i][j] = fzero4();

  for (int k0 = 0; k0 < Kd; k0 += 32) {
    short8 va0 = *(const short8*)(pa0 + k0);
    short8 va1 = *(const short8*)(pa1 + k0);
    short8 vb0 = *(const short8*)(pb0 + k0);
    short8 vb1 = *(const short8*)(pb1 + k0);
    __syncthreads();
    *(short8*)&sA[r0 * 32 + ko0] = va0;
    *(short8*)&sA[(64 + r0) * 32 + ko0] = va1;
    *(short8*)&sB[r0 * 32 + ko0] = vb0;
    *(short8*)&sB[(64 + r0) * 32 + ko0] = vb1;
    __syncthreads();
    short8 af[4], bfr[4];
#pragma unroll
    for (int i = 0; i < 4; ++i)
      af[i] = *(const short8*)&sA[(wr * 64 + i * 16 + li) * 32 + lg * 8];
#pragma unroll
    for (int j = 0; j < 4; ++j)
      bfr[j] = *(const short8*)&sB[(wc * 64 + j * 16 + li) * 32 + lg * 8];
#pragma unroll
    for (int i = 0; i < 4; ++i)
#pragma unroll
      for (int j = 0; j < 4; ++j)
        acc[i][j] = __builtin_amdgcn_mfma_f32_16x16x32_bf16(af[i], bfr[j], acc[i][j], 0, 0, 0);
  }

  // epilogue: D frag mapping col = li, row = lg*4 + r  [m89/m91 verified]
#pragma unroll
  for (int i = 0; i < 4; ++i) {
#pragma unroll
    for (int j = 0; j < 4; ++j) {
      const int ng = n0 + wc * 64 + j * 16 + li;
      const float bs = bias[ng];
#pragma unroll
      for (int r = 0; r < 4; ++r) {
        const int mg = m0 + wr * 64 + i * 16 + lg * 4 + r;
        const float v = acc[i][j][r] + bs;
        if (MODE == 0) {
          const int bb = mg >> 11, t = mg & 2047;
          const int d = ng & 63;
          if (ng < 1024) {
            const int h = ng >> 6;
            Qo[(((size_t)bb * 16 + h) * 2048 + t) * 64 + d] = __float2bfloat16(v * 0.125f);
          } else if (ng < 2048) {
            const int h = (ng - 1024) >> 6;
            Ko[(((size_t)bb * 16 + h) * 2048 + t) * 64 + d] = __float2bfloat16(v);
          } else {
            const int h = (ng - 2048) >> 6;
            Vo[(((size_t)bb * 16 + h) * 64 + d) * 2048 + t] = __float2bfloat16(v);
          }
        } else {
          Fo[(size_t)mg * N + ng] = v;
        }
      }
    }
  }
}

// ---------------- flash attention: one wave per (b,h,16-row q-tile) ----------------
// Q pre-scaled by 1/8.  K/V served from L2 (256KB/head).  Vt is [b,h,64,T].
__global__ __launch_bounds__(256) void k_attn(
    const bf16* __restrict__ Q, const bf16* __restrict__ K,
    const bf16* __restrict__ Vt, bf16* __restrict__ Y) {
  __shared__ bf16 P[4][16 * 32];
  const int w = threadIdx.x >> 6, l = threadIdx.x & 63;
  const int lg = l >> 4, li = l & 15;
  const int gw = blockIdx.x * 4 + w;
  const int bh = gw >> 7, qt = gw & 127;   // 128 q-tiles of 16 per head
  const int b = bh >> 4, h = bh & 15;

  const bf16* Qp = Q + ((size_t)bh * 2048 + qt * 16) * 64;
  const bf16* Kp = K + (size_t)bh * 2048 * 64;
  const bf16* Vp = Vt + (size_t)bh * 64 * 2048;

  // Q a-frags: row = li, k-chunk = lg*8 (+0 / +32)
  const short8 aq0 = *(const short8*)(Qp + li * 64 + lg * 8);
  const short8 aq1 = *(const short8*)(Qp + li * 64 + 32 + lg * 8);

  floatx4 o[4];
#pragma unroll
  for (int f = 0; f < 4; ++f) o[f] = fzero4();
  float mrow[4] = {-INFINITY, -INFINITY, -INFINITY, -INFINITY};
  float lsum[4] = {0.f, 0.f, 0.f, 0.f};

  const int qbase = qt * 16 + lg * 4;
  const int limit = qt * 16 + 16;           // keys needed: 0..limit-1
  bf16* pl = &P[w][0];

  for (int k0 = 0; k0 < limit; k0 += 32) {
    floatx4 s0 = fzero4(), s1 = fzero4();
    {
      const bf16* kp = Kp + (size_t)(k0 + li) * 64;
      short8 kb0 = *(const short8*)(kp + lg * 8);
      short8 kb1 = *(const short8*)(kp + 32 + lg * 8);
      s0 = __builtin_amdgcn_mfma_f32_16x16x32_bf16(aq0, kb0, s0, 0, 0, 0);
      s0 = __builtin_amdgcn_mfma_f32_16x16x32_bf16(aq1, kb1, s0, 0, 0, 0);
    }
    {
      const bf16* kp = Kp + (size_t)(k0 + 16 + li) * 64;
      short8 kb0 = *(const short8*)(kp + lg * 8);
      short8 kb1 = *(const short8*)(kp + 32 + lg * 8);
      s1 = __builtin_amdgcn_mfma_f32_16x16x32_bf16(aq0, kb0, s1, 0, 0, 0);
      s1 = __builtin_amdgcn_mfma_f32_16x16x32_bf16(aq1, kb1, s1, 0, 0, 0);
    }
    const int kg0 = k0 + li, kg1 = k0 + 16 + li;
    float al[4], p0[4], p1[4];
#pragma unroll
    for (int r = 0; r < 4; ++r) {
      const int qg = qbase + r;
      float v0 = (kg0 <= qg) ? s0[r] : -INFINITY;
      float v1 = (kg1 <= qg) ? s1[r] : -INFINITY;
      float pm = fmaxf(v0, v1);
      pm = fmaxf(pm, __shfl_xor(pm, 1));
      pm = fmaxf(pm, __shfl_xor(pm, 2));
      pm = fmaxf(pm, __shfl_xor(pm, 4));
      pm = fmaxf(pm, __shfl_xor(pm, 8));
      const float mn = fmaxf(mrow[r], pm);
      const float a = __expf(mrow[r] - mn);   // first iter: exp(-inf)=0, o is 0 anyway
      mrow[r] = mn;
      const float e0 = __expf(v0 - mn);       // masked: exp(-inf)=0
      const float e1 = __expf(v1 - mn);
      float rs = e0 + e1;
      rs += __shfl_xor(rs, 1);
      rs += __shfl_xor(rs, 2);
      rs += __shfl_xor(rs, 4);
      rs += __shfl_xor(rs, 8);
      lsum[r] = lsum[r] * a + rs;
      al[r] = a; p0[r] = e0; p1[r] = e1;
    }
#pragma unroll
    for (int f = 0; f < 4; ++f) {
      o[f][0] *= al[0]; o[f][1] *= al[1]; o[f][2] *= al[2]; o[f][3] *= al[3];
    }
    // P round-trip through per-wave LDS (same-wave DS ops are in-order; no barrier)
#pragma unroll
    for (int r = 0; r < 4; ++r) {
      pl[(lg * 4 + r) * 32 + li]      = __float2bfloat16(p0[r]);
      pl[(lg * 4 + r) * 32 + 16 + li] = __float2bfloat16(p1[r]);
    }
    const short8 pa = *(const short8*)&pl[li * 32 + lg * 8];
#pragma unroll
    for (int f = 0; f < 4; ++f) {
      const short8 bv = *(const short8*)(Vp + (size_t)(f * 16 + li) * 2048 + k0 + lg * 8);
      o[f] = __builtin_amdgcn_mfma_f32_16x16x32_bf16(pa, bv, o[f], 0, 0, 0);
    }
  }
#pragma unroll
  for (int r = 0; r < 4; ++r) {
    const int qg = qt * 16 + lg * 4 + r;
    const float inv = 1.0f / lsum[r];
    const size_t base = ((size_t)b * 2048 + qg) * 1024 + h * 64;
#pragma unroll
    for (int f = 0; f < 4; ++f)
      Y[base + f * 16 + li] = __float2bfloat16(o[f][r] * inv);
  }
}

// ---------------- launch ----------------
// B=4, T=2048, C=1024, H=16, hd=64.  M=8192.
// ws layout (bytes):
//   Wt_attn  [3072,1024] bf16 :        0 ..  6291456
//   Wt_proj  [1024,1024] bf16 :  6291456 ..  8388608
//   Q  [B,H,T,64] bf16        :  8388608 .. 25165824
//   K  [B,H,T,64] bf16        : 25165824 .. 41943040
//   Vt [B,H,64,T] bf16        : 41943040 .. 58720256
//   x_bf / Y (aliased) bf16   : 58720256 .. 75497472   (x_bf dead after GEMM1)
extern "C" void kernel_launch(void* const* d_in, const int* in_sizes, int n_in,
                              void* d_out, int out_size, void* d_ws, size_t ws_size,
                              hipStream_t stream) {
  const float* x      = (const float*)d_in[0];
  const float* W_attn = (const float*)d_in[1];
  const float* b_attn = (const float*)d_in[2];
  const float* W_proj = (const float*)d_in[3];
  const float* b_proj = (const float*)d_in[4];
  float* out = (float*)d_out;

  char* ws = (char*)d_ws;
  bf16* Wt_a = (bf16*)(ws);
  bf16* Wt_p = (bf16*)(ws + 6291456);
  bf16* Qb   = (bf16*)(ws + 8388608);
  bf16* Kb   = (bf16*)(ws + 25165824);
  bf16* Vtb  = (bf16*)(ws + 41943040);
  bf16* x_bf = (bf16*)(ws + 58720256);
  bf16* Yb   = x_bf;  // alias: x_bf dead after GEMM1

  k_cast<<<4096, 256, 0, stream>>>(x, x_bf, 8388608);
  k_transpose<<<dim3(96, 32), dim3(32, 8), 0, stream>>>(W_attn, Wt_a, 1024, 3072);
  k_transpose<<<dim3(32, 32), dim3(32, 8), 0, stream>>>(W_proj, Wt_p, 1024, 1024);
  k_gemm<0><<<dim3(24, 64), 256, 0, stream>>>(x_bf, Wt_a, b_attn, Qb, Kb, Vtb,
                                              nullptr, 8192, 3072, 1024);
  k_attn<<<2048, 256, 0, stream>>>(Qb, Kb, Vtb, Yb);
  k_gemm<1><<<dim3(8, 64), 256, 0, stream>>>(Yb, Wt_p, b_proj, nullptr, nullptr,
                                             nullptr, out, 8192, 1024, 1024);
}

// Round 3
// 285.989 us; speedup vs baseline: 2.0396x; 2.0396x over previous
//
#include <hip/hip_runtime.h>
#include <hip/hip_bf16.h>
#include <math.h>

typedef __attribute__((ext_vector_type(8))) short short8;
typedef __attribute__((ext_vector_type(4))) float floatx4;
using bf16 = __hip_bfloat16;

#define DEVI __device__ __forceinline__

DEVI floatx4 fzero4() { floatx4 z; z[0]=0.f; z[1]=0.f; z[2]=0.f; z[3]=0.f; return z; }

DEVI unsigned short f2b(float x) {
  union { bf16 h; unsigned short u; } c;
  c.h = __float2bfloat16(x);
  return c.u;
}

// async global->LDS, 16B per lane; lds dest must be wave-uniform base (+lane*16 implicit)
DEVI void gload16(const bf16* g, bf16* l) {
  typedef __attribute__((address_space(1))) const void gv_t;
  typedef __attribute__((address_space(3))) void lv_t;
  __builtin_amdgcn_global_load_lds((gv_t*)g, (lv_t*)l, 16, 0, 0);
}

// ---------------- cast f32 -> bf16 (8 elems/thread, vectorized) ----------------
__global__ __launch_bounds__(256) void k_cast(const float* __restrict__ in,
                                              bf16* __restrict__ out, int n) {
  int i = (blockIdx.x * 256 + threadIdx.x) * 8;
  if (i >= n) return;
  float4 a = *(const float4*)(in + i);
  float4 b = *(const float4*)(in + i + 4);
  short8 v;
  v[0] = (short)f2b(a.x); v[1] = (short)f2b(a.y);
  v[2] = (short)f2b(a.z); v[3] = (short)f2b(a.w);
  v[4] = (short)f2b(b.x); v[5] = (short)f2b(b.y);
  v[6] = (short)f2b(b.z); v[7] = (short)f2b(b.w);
  *(short8*)(out + i) = v;
}

// ---------------- transpose + cast: out[c][r] = in[r][c] ----------------
__global__ __launch_bounds__(256) void k_transpose(const float* __restrict__ in,
                                                   bf16* __restrict__ out,
                                                   int R, int C) {
  __shared__ float tile[32][33];
  int x = blockIdx.x * 32 + threadIdx.x;
  for (int i = threadIdx.y; i < 32; i += 8) {
    int y = blockIdx.y * 32 + i;
    tile[i][threadIdx.x] = (y < R && x < C) ? in[(size_t)y * C + x] : 0.f;
  }
  __syncthreads();
  int ox = blockIdx.y * 32 + threadIdx.x;
  for (int i = threadIdx.y; i < 32; i += 8) {
    int oy = blockIdx.x * 32 + i;
    if (oy < C && ox < R) out[(size_t)oy * R + ox] = __float2bfloat16(tile[threadIdx.x][i]);
  }
}

// ---------------- GEMM: C = A[M,K] @ Bt[N,K]^T + bias ----------------
// 128x128 tile, BK=32, 4 waves (2x2), global_load_lds staging (m97 structure).
// LDS tile = 4096 bf16 elements; rows 64-127 start at ELEMENT offset 2048.
template<int MODE>
__global__ __launch_bounds__(256) void k_gemm(
    const bf16* __restrict__ A, const bf16* __restrict__ Bt,
    const float* __restrict__ bias,
    bf16* __restrict__ Qo, bf16* __restrict__ Ko, bf16* __restrict__ Vo,
    float* __restrict__ Fo, int M, int N, int Kd) {
  __shared__ bf16 sA[128 * 32];
  __shared__ bf16 sB[128 * 32];
  const int tid = threadIdx.x;
  const int w = tid >> 6, l = tid & 63;
  const int lg = l >> 4, li = l & 15;
  const int wr = w >> 1, wc = w & 1;
  const int m0 = blockIdx.y * 128, n0 = blockIdx.x * 128;

  // staging: 512 chunks of 16B; wave w lanes cover rows w*16+(l>>2), k-off (l&3)*8
  // -> LDS element w*512 + l*8 (linear).  Second half: +2048 elements (rows 64-127).
  const int r0 = tid >> 2, ko0 = (tid & 3) * 8;
  const bf16* pa0 = A + (size_t)(m0 + r0) * Kd + ko0;
  const bf16* pa1 = A + (size_t)(m0 + 64 + r0) * Kd + ko0;
  const bf16* pb0 = Bt + (size_t)(n0 + r0) * Kd + ko0;
  const bf16* pb1 = Bt + (size_t)(n0 + 64 + r0) * Kd + ko0;

  floatx4 acc[4][4];
#pragma unroll
  for (int i = 0; i < 4; ++i)
#pragma unroll
    for (int j = 0; j < 4; ++j) acc[i][j] = fzero4();

  for (int k0 = 0; k0 < Kd; k0 += 32) {
    __syncthreads();   // previous iteration's frag reads done before overwrite
    gload16(pa0 + k0, sA + w * 512);
    gload16(pa1 + k0, sA + 2048 + w * 512);
    gload16(pb0 + k0, sB + w * 512);
    gload16(pb1 + k0, sB + 2048 + w * 512);
    __syncthreads();   // drains vmcnt(0): staging complete
    short8 af[4], bfr[4];
#pragma unroll
    for (int i = 0; i < 4; ++i)
      af[i] = *(const short8*)&sA[(wr * 64 + i * 16 + li) * 32 + lg * 8];
#pragma unroll
    for (int j = 0; j < 4; ++j)
      bfr[j] = *(const short8*)&sB[(wc * 64 + j * 16 + li) * 32 + lg * 8];
#pragma unroll
    for (int i = 0; i < 4; ++i)
#pragma unroll
      for (int j = 0; j < 4; ++j)
        acc[i][j] = __builtin_amdgcn_mfma_f32_16x16x32_bf16(af[i], bfr[j], acc[i][j], 0, 0, 0);
  }

  // epilogue: D frag mapping col = li, row = lg*4 + r  [m89/m91 verified]
#pragma unroll
  for (int i = 0; i < 4; ++i) {
#pragma unroll
    for (int j = 0; j < 4; ++j) {
      const int ng = n0 + wc * 64 + j * 16 + li;
      const float bs = bias[ng];
#pragma unroll
      for (int r = 0; r < 4; ++r) {
        const int mg = m0 + wr * 64 + i * 16 + lg * 4 + r;
        const float v = acc[i][j][r] + bs;
        if (MODE == 0) {
          const int bb = mg >> 11, t = mg & 2047;
          const int d = ng & 63;
          if (ng < 1024) {
            const int h = ng >> 6;
            Qo[(((size_t)bb * 16 + h) * 2048 + t) * 64 + d] = __float2bfloat16(v * 0.125f);
          } else if (ng < 2048) {
            const int h = (ng - 1024) >> 6;
            Ko[(((size_t)bb * 16 + h) * 2048 + t) * 64 + d] = __float2bfloat16(v);
          } else {
            const int h = (ng - 2048) >> 6;
            Vo[(((size_t)bb * 16 + h) * 64 + d) * 2048 + t] = __float2bfloat16(v);
          }
        } else {
          Fo[(size_t)mg * N + ng] = v;
        }
      }
    }
  }
}

// ---------------- flash attention v2 ----------------
// Block = 4 waves x 32 q-rows = 128 rows.  Pairing: block handles q-tile tb and
// 15-tb sequentially -> uniform 34 steps of 64 keys per block.  K [64][64] and
// Vt [64][64] LDS-staged (double-buffered, global_load_lds w=16, XOR-swizzled
// 16B chunks: chunk' = chunk ^ (row&7), pre-swizzled at the global source).
#define T_SEQ 2048
#define PSTR 76

__global__ __launch_bounds__(256) void k_attn(
    const bf16* __restrict__ Q, const bf16* __restrict__ K,
    const bf16* __restrict__ Vt, bf16* __restrict__ Y) {
  __shared__ bf16 sK[2][64 * 64];
  __shared__ bf16 sV[2][64 * 64];
  __shared__ bf16 sP[4][32 * PSTR];

  const int tid = threadIdx.x;
  const int w = tid >> 6, l = tid & 63;
  const int lg = l >> 4, li = l & 15;
  const int bh = blockIdx.x >> 3;
  const int pb = blockIdx.x & 7;
  const int b = bh >> 4, h = bh & 15;

  const bf16* Qp = Q + (size_t)bh * (T_SEQ * 64);
  const bf16* Kp = K + (size_t)bh * (T_SEQ * 64);
  const bf16* Vp = Vt + (size_t)bh * (64 * T_SEQ);
  bf16* pw = &sP[w][0];

  for (int ph = 0; ph < 2; ++ph) {
    const int tb = (ph == 0) ? pb : 15 - pb;
    const int q0 = tb * 128;
    const int wq0 = q0 + w * 32;
    const int nst = (q0 + 128) >> 6;

    // Q A-frags: row=li (q), k=lg*8 within d-chunk dc*32
    short8 aq[2][2];
#pragma unroll
    for (int rg = 0; rg < 2; ++rg)
#pragma unroll
      for (int dc = 0; dc < 2; ++dc)
        aq[rg][dc] = *(const short8*)(Qp + (size_t)(wq0 + rg * 16 + li) * 64 + dc * 32 + lg * 8);

    floatx4 o[2][4];
    float mrow[2][4], lsum[2][4];
#pragma unroll
    for (int rg = 0; rg < 2; ++rg)
#pragma unroll
      for (int f = 0; f < 4; ++f) o[rg][f] = fzero4();
#pragma unroll
    for (int rg = 0; rg < 2; ++rg)
#pragma unroll
      for (int r = 0; r < 4; ++r) { mrow[rg][r] = -INFINITY; lsum[rg][r] = 0.f; }

    // stage(buf, k0): K rows k0..k0+63 (64 d) and Vt rows 0..63 (k0..k0+63).
    // chunk c in [0,512): row=c>>3, slot=c&7, src chunk = slot ^ (row&7).
    auto STAGE = [&](int buf, int k0) {
#pragma unroll
      for (int half = 0; half < 2; ++half) {
        const int c = half * 256 + tid;
        const int row = c >> 3, cs = c & 7;
        const int sc = cs ^ (row & 7);
        bf16* kb = &sK[buf][(half * 256 + w * 64) * 8];   // wave-uniform base
        bf16* vb = &sV[buf][(half * 256 + w * 64) * 8];
        gload16(Kp + (size_t)(k0 + row) * 64 + sc * 8, kb);
        gload16(Vp + (size_t)row * T_SEQ + k0 + sc * 8, vb);
      }
    };

    int cur = 0;
    STAGE(0, 0);
    __syncthreads();
    for (int t = 0; t < nst; ++t) {
      const int k0 = t << 6;
      if (t + 1 < nst) STAGE(cur ^ 1, k0 + 64);   // prefetch flies during compute
      if (k0 <= wq0 + 31) {
        // ---- QK^T: s[rg][kt] over 64 keys, d=64 ----
        floatx4 s[2][4];
#pragma unroll
        for (int kt = 0; kt < 4; ++kt) {
          const int rowk = kt * 16 + li;
          const short8 kb0 = *(const short8*)&sK[cur][rowk * 64 + ((lg ^ (rowk & 7)) * 8)];
          const short8 kb1 = *(const short8*)&sK[cur][rowk * 64 + (((4 + lg) ^ (rowk & 7)) * 8)];
#pragma unroll
          for (int rg = 0; rg < 2; ++rg) {
            floatx4 acc = __builtin_amdgcn_mfma_f32_16x16x32_bf16(aq[rg][0], kb0, fzero4(), 0, 0, 0);
            s[rg][kt] = __builtin_amdgcn_mfma_f32_16x16x32_bf16(aq[rg][1], kb1, acc, 0, 0, 0);
          }
        }
        // ---- causal mask (only the diagonal step needs it) ----
        if (k0 + 63 > wq0) {
#pragma unroll
          for (int rg = 0; rg < 2; ++rg)
#pragma unroll
            for (int kt = 0; kt < 4; ++kt) {
              const int kg = k0 + kt * 16 + li;
#pragma unroll
              for (int r = 0; r < 4; ++r) {
                const int qg = wq0 + rg * 16 + lg * 4 + r;
                if (kg > qg) s[rg][kt][r] = -1e30f;
              }
            }
        }
        // ---- online softmax (16-lane shfl reduce over li) ----
        float a_[2][4];
#pragma unroll
        for (int rg = 0; rg < 2; ++rg)
#pragma unroll
          for (int r = 0; r < 4; ++r) {
            float pm = fmaxf(fmaxf(s[rg][0][r], s[rg][1][r]), fmaxf(s[rg][2][r], s[rg][3][r]));
            pm = fmaxf(pm, __shfl_xor(pm, 1));
            pm = fmaxf(pm, __shfl_xor(pm, 2));
            pm = fmaxf(pm, __shfl_xor(pm, 4));
            pm = fmaxf(pm, __shfl_xor(pm, 8));
            const float mn = fmaxf(mrow[rg][r], pm);
            const float a = __expf(mrow[rg][r] - mn);
            mrow[rg][r] = mn;
            const float e0 = __expf(s[rg][0][r] - mn);
            const float e1 = __expf(s[rg][1][r] - mn);
            const float e2 = __expf(s[rg][2][r] - mn);
            const float e3 = __expf(s[rg][3][r] - mn);
            s[rg][0][r] = e0; s[rg][1][r] = e1; s[rg][2][r] = e2; s[rg][3][r] = e3;
            float rs = (e0 + e1) + (e2 + e3);
            rs += __shfl_xor(rs, 1);
            rs += __shfl_xor(rs, 2);
            rs += __shfl_xor(rs, 4);
            rs += __shfl_xor(rs, 8);
            lsum[rg][r] = lsum[rg][r] * a + rs;
            a_[rg][r] = a;
          }
#pragma unroll
        for (int rg = 0; rg < 2; ++rg)
#pragma unroll
          for (int f = 0; f < 4; ++f) {
            o[rg][f][0] *= a_[rg][0]; o[rg][f][1] *= a_[rg][1];
            o[rg][f][2] *= a_[rg][2]; o[rg][f][3] *= a_[rg][3];
          }
        // ---- P -> per-wave LDS (padded rows), then A-frags (same-wave, in-order) ----
#pragma unroll
        for (int rg = 0; rg < 2; ++rg)
#pragma unroll
          for (int r = 0; r < 4; ++r)
#pragma unroll
            for (int kt = 0; kt < 4; ++kt)
              pw[(rg * 16 + lg * 4 + r) * PSTR + kt * 16 + li] = __float2bfloat16(s[rg][kt][r]);
        short8 pa[2][2];
#pragma unroll
        for (int rg = 0; rg < 2; ++rg)
#pragma unroll
          for (int kc = 0; kc < 2; ++kc)
            pa[rg][kc] = *(const short8*)&pw[(rg * 16 + li) * PSTR + kc * 32 + lg * 8];
        // ---- PV: o[rg][f] += P[32q x 64k] @ V[64k x 64d] ----
#pragma unroll
        for (int f = 0; f < 4; ++f)
#pragma unroll
          for (int kc = 0; kc < 2; ++kc) {
            const int rowv = f * 16 + li;
            const short8 vb = *(const short8*)&sV[cur][rowv * 64 + (((kc * 4 + lg) ^ (rowv & 7)) * 8)];
            o[0][f] = __builtin_amdgcn_mfma_f32_16x16x32_bf16(pa[0][kc], vb, o[0][f], 0, 0, 0);
            o[1][f] = __builtin_amdgcn_mfma_f32_16x16x32_bf16(pa[1][kc], vb, o[1][f], 0, 0, 0);
          }
      }
      __syncthreads();   // drains prefetch vmcnt + all waves done reading cur
      cur ^= 1;
    }
    // ---- epilogue: normalize + write Y [B,T,C] bf16 ----
#pragma unroll
    for (int rg = 0; rg < 2; ++rg)
#pragma unroll
      for (int r = 0; r < 4; ++r) {
        const int qg = wq0 + rg * 16 + lg * 4 + r;
        const float inv = 1.0f / lsum[rg][r];
        const size_t base = ((size_t)b * T_SEQ + qg) * 1024 + h * 64;
#pragma unroll
        for (int f = 0; f < 4; ++f)
          Y[base + f * 16 + li] = __float2bfloat16(o[rg][f][r] * inv);
      }
  }
}

// ---------------- launch ----------------
extern "C" void kernel_launch(void* const* d_in, const int* in_sizes, int n_in,
                              void* d_out, int out_size, void* d_ws, size_t ws_size,
                              hipStream_t stream) {
  const float* x      = (const float*)d_in[0];
  const float* W_attn = (const float*)d_in[1];
  const float* b_attn = (const float*)d_in[2];
  const float* W_proj = (const float*)d_in[3];
  const float* b_proj = (const float*)d_in[4];
  float* out = (float*)d_out;

  char* ws = (char*)d_ws;
  bf16* Wt_a = (bf16*)(ws);
  bf16* Wt_p = (bf16*)(ws + 6291456);
  bf16* Qb   = (bf16*)(ws + 8388608);
  bf16* Kb   = (bf16*)(ws + 25165824);
  bf16* Vtb  = (bf16*)(ws + 41943040);
  bf16* x_bf = (bf16*)(ws + 58720256);
  bf16* Yb   = x_bf;  // alias: x_bf dead after GEMM1

  k_cast<<<4096, 256, 0, stream>>>(x, x_bf, 8388608);
  k_transpose<<<dim3(96, 32), dim3(32, 8), 0, stream>>>(W_attn, Wt_a, 1024, 3072);
  k_transpose<<<dim3(32, 32), dim3(32, 8), 0, stream>>>(W_proj, Wt_p, 1024, 1024);
  k_gemm<0><<<dim3(24, 64), 256, 0, stream>>>(x_bf, Wt_a, b_attn, Qb, Kb, Vtb,
                                              nullptr, 8192, 3072, 1024);
  k_attn<<<512, 256, 0, stream>>>(Qb, Kb, Vtb, Yb);
  k_gemm<1><<<dim3(8, 64), 256, 0, stream>>>(Yb, Wt_p, b_proj, nullptr, nullptr,
                                             nullptr, out, 8192, 1024, 1024);
}

// Round 5
// 241.572 us; speedup vs baseline: 2.4146x; 1.1839x over previous
//
#include <hip/hip_runtime.h>
#include <hip/hip_bf16.h>
#include <math.h>

typedef __attribute__((ext_vector_type(8))) short short8;
typedef __attribute__((ext_vector_type(4))) float floatx4;
using bf16 = __hip_bfloat16;

#define DEVI __device__ __forceinline__

DEVI floatx4 fzero4() { floatx4 z; z[0]=0.f; z[1]=0.f; z[2]=0.f; z[3]=0.f; return z; }

DEVI unsigned short f2b(float x) {
  union { bf16 h; unsigned short u; } c;
  c.h = __float2bfloat16(x);
  return c.u;
}

DEVI unsigned pack2(float a, float b) {
  return (unsigned)f2b(a) | ((unsigned)f2b(b) << 16);
}

// async global->LDS, 16B per lane; lds dest must be wave-uniform base (+lane*16 implicit)
DEVI void gload16(const bf16* g, bf16* l) {
  typedef __attribute__((address_space(1))) const void gv_t;
  typedef __attribute__((address_space(3))) void lv_t;
  __builtin_amdgcn_global_load_lds((gv_t*)g, (lv_t*)l, 16, 0, 0);
}

// ---------------- cast f32 -> bf16 (8 elems/thread, vectorized) ----------------
__global__ __launch_bounds__(256) void k_cast(const float* __restrict__ in,
                                              bf16* __restrict__ out, int n) {
  int i = (blockIdx.x * 256 + threadIdx.x) * 8;
  if (i >= n) return;
  float4 a = *(const float4*)(in + i);
  float4 b = *(const float4*)(in + i + 4);
  short8 v;
  v[0] = (short)f2b(a.x); v[1] = (short)f2b(a.y);
  v[2] = (short)f2b(a.z); v[3] = (short)f2b(a.w);
  v[4] = (short)f2b(b.x); v[5] = (short)f2b(b.y);
  v[6] = (short)f2b(b.z); v[7] = (short)f2b(b.w);
  *(short8*)(out + i) = v;
}

// ---------------- transpose + cast: out[c][r] = in[r][c] ----------------
__global__ __launch_bounds__(256) void k_transpose(const float* __restrict__ in,
                                                   bf16* __restrict__ out,
                                                   int R, int C) {
  __shared__ float tile[32][33];
  int x = blockIdx.x * 32 + threadIdx.x;
  for (int i = threadIdx.y; i < 32; i += 8) {
    int y = blockIdx.y * 32 + i;
    tile[i][threadIdx.x] = (y < R && x < C) ? in[(size_t)y * C + x] : 0.f;
  }
  __syncthreads();
  int ox = blockIdx.y * 32 + threadIdx.x;
  for (int i = threadIdx.y; i < 32; i += 8) {
    int oy = blockIdx.x * 32 + i;
    if (oy < C && ox < R) out[(size_t)oy * R + ox] = __float2bfloat16(tile[threadIdx.x][i]);
  }
}

// ---------------- GEMM: C = A[M,K] @ Bt[N,K]^T + bias ----------------
// 128x128 tile, BK=32, 4 waves (2x2), global_load_lds staging (m97 structure).
// LDS tile = 4096 bf16 elements; rows 64-127 start at ELEMENT offset 2048.
template<int MODE>
__global__ __launch_bounds__(256) void k_gemm(
    const bf16* __restrict__ A, const bf16* __restrict__ Bt,
    const float* __restrict__ bias,
    bf16* __restrict__ Qo, bf16* __restrict__ Ko, bf16* __restrict__ Vo,
    float* __restrict__ Fo, int M, int N, int Kd) {
  __shared__ bf16 sA[128 * 32];
  __shared__ bf16 sB[128 * 32];
  const int tid = threadIdx.x;
  const int w = tid >> 6, l = tid & 63;
  const int lg = l >> 4, li = l & 15;
  const int wr = w >> 1, wc = w & 1;
  const int m0 = blockIdx.y * 128, n0 = blockIdx.x * 128;

  const int r0 = tid >> 2, ko0 = (tid & 3) * 8;
  const bf16* pa0 = A + (size_t)(m0 + r0) * Kd + ko0;
  const bf16* pa1 = A + (size_t)(m0 + 64 + r0) * Kd + ko0;
  const bf16* pb0 = Bt + (size_t)(n0 + r0) * Kd + ko0;
  const bf16* pb1 = Bt + (size_t)(n0 + 64 + r0) * Kd + ko0;

  floatx4 acc[4][4];
#pragma unroll
  for (int i = 0; i < 4; ++i)
#pragma unroll
    for (int j = 0; j < 4; ++j) acc[i][j] = fzero4();

  for (int k0 = 0; k0 < Kd; k0 += 32) {
    __syncthreads();
    gload16(pa0 + k0, sA + w * 512);
    gload16(pa1 + k0, sA + 2048 + w * 512);
    gload16(pb0 + k0, sB + w * 512);
    gload16(pb1 + k0, sB + 2048 + w * 512);
    __syncthreads();
    short8 af[4], bfr[4];
#pragma unroll
    for (int i = 0; i < 4; ++i)
      af[i] = *(const short8*)&sA[(wr * 64 + i * 16 + li) * 32 + lg * 8];
#pragma unroll
    for (int j = 0; j < 4; ++j)
      bfr[j] = *(const short8*)&sB[(wc * 64 + j * 16 + li) * 32 + lg * 8];
#pragma unroll
    for (int i = 0; i < 4; ++i)
#pragma unroll
      for (int j = 0; j < 4; ++j)
        acc[i][j] = __builtin_amdgcn_mfma_f32_16x16x32_bf16(af[i], bfr[j], acc[i][j], 0, 0, 0);
  }

  // epilogue: D frag mapping col = li, row = lg*4 + r  [m89/m91 verified]
#pragma unroll
  for (int i = 0; i < 4; ++i) {
#pragma unroll
    for (int j = 0; j < 4; ++j) {
      const int ng = n0 + wc * 64 + j * 16 + li;
      const float bs = bias[ng];
#pragma unroll
      for (int r = 0; r < 4; ++r) {
        const int mg = m0 + wr * 64 + i * 16 + lg * 4 + r;
        const float v = acc[i][j][r] + bs;
        if (MODE == 0) {
          const int bb = mg >> 11, t = mg & 2047;
          const int d = ng & 63;
          if (ng < 1024) {
            const int h = ng >> 6;
            Qo[(((size_t)bb * 16 + h) * 2048 + t) * 64 + d] = __float2bfloat16(v * 0.125f);
          } else if (ng < 2048) {
            const int h = (ng - 1024) >> 6;
            Ko[(((size_t)bb * 16 + h) * 2048 + t) * 64 + d] = __float2bfloat16(v);
          } else {
            const int h = (ng - 2048) >> 6;
            Vo[(((size_t)bb * 16 + h) * 64 + d) * 2048 + t] = __float2bfloat16(v);
          }
        } else {
          Fo[(size_t)mg * N + ng] = v;
        }
      }
    }
  }
}

// ---------------- flash attention v3: swapped QK^T, in-lane softmax ----------------
// Block = 4 waves x 32 q-rows.  Pairing: q-tiles tb and 15-tb -> uniform 34 steps.
// Swapped mfma(K,Q): lane owns q-row li (per rg half), 16 k-values in-register
// (k = kt*16 + lg*4 + r).  Row-max: in-lane tree + 2 shfl (vs 32).  Row-sum:
// in-lane partial, reduced once at epilogue.  Defer-max (THR=8) skips o-rescale.
// K/V LDS double-buffered via gload16, XOR-swizzled chunks (round-3 verified).
#define T_SEQ 2048
#define PSTR 78

__global__ __launch_bounds__(256) void k_attn(
    const bf16* __restrict__ Q, const bf16* __restrict__ K,
    const bf16* __restrict__ Vt, bf16* __restrict__ Y) {
  __shared__ bf16 sK[2][64 * 64];
  __shared__ bf16 sV[2][64 * 64];
  __shared__ bf16 sP[4][32 * PSTR];

  const int tid = threadIdx.x;
  const int w = tid >> 6, l = tid & 63;
  const int lg = l >> 4, li = l & 15;
  // XCD swizzle: 512 blocks, 8 XCDs -> all 8 pb-blocks of a head on one XCD (L2 K/V reuse)
  const int bid = blockIdx.x;
  const int swz = (bid & 7) * 64 + (bid >> 3);
  const int bh = swz >> 3;
  const int pb = swz & 7;
  const int b = bh >> 4, h = bh & 15;

  const bf16* Qp = Q + (size_t)bh * (T_SEQ * 64);
  const bf16* Kp = K + (size_t)bh * (T_SEQ * 64);
  const bf16* Vp = Vt + (size_t)bh * (64 * T_SEQ);
  bf16* pw = &sP[w][0];

  for (int ph = 0; ph < 2; ++ph) {
    const int tb = (ph == 0) ? pb : 15 - pb;
    const int q0 = tb * 128;
    const int wq0 = q0 + w * 32;
    const int nst = (q0 + 128) >> 6;

    // Q B-frags (swapped mfma): row q = wq0+rg*16+li, d-chunk dc*32+lg*8
    short8 aq[2][2];
#pragma unroll
    for (int rg = 0; rg < 2; ++rg)
#pragma unroll
      for (int dc = 0; dc < 2; ++dc)
        aq[rg][dc] = *(const short8*)(Qp + (size_t)(wq0 + rg * 16 + li) * 64 + dc * 32 + lg * 8);

    floatx4 o[2][4];
#pragma unroll
    for (int rg = 0; rg < 2; ++rg)
#pragma unroll
      for (int f = 0; f < 4; ++f) o[rg][f] = fzero4();
    float m[2] = {-INFINITY, -INFINITY};
    float lsum[2] = {0.f, 0.f};   // partial over this lane's 16-k groups

    auto STAGE = [&](int buf, int k0) {
#pragma unroll
      for (int half = 0; half < 2; ++half) {
        const int c = half * 256 + tid;
        const int row = c >> 3, cs = c & 7;
        const int sc = cs ^ (row & 7);
        bf16* kb = &sK[buf][(half * 256 + w * 64) * 8];
        bf16* vb = &sV[buf][(half * 256 + w * 64) * 8];
        gload16(Kp + (size_t)(k0 + row) * 64 + sc * 8, kb);
        gload16(Vp + (size_t)row * T_SEQ + k0 + sc * 8, vb);
      }
    };

    int cur = 0;
    STAGE(0, 0);
    __syncthreads();
    for (int t = 0; t < nst; ++t) {
      const int k0 = t << 6;
      if (t + 1 < nst) STAGE(cur ^ 1, k0 + 64);
      if (k0 <= wq0 + 31) {
        // ---- swapped QK^T: s[rg][kt]: lane holds q=li(+rg*16), k=kt*16+lg*4+r ----
        floatx4 s[2][4];
#pragma unroll
        for (int kt = 0; kt < 4; ++kt) {
          const int rowk = kt * 16 + li;
          const short8 kb0 = *(const short8*)&sK[cur][rowk * 64 + ((lg ^ (rowk & 7)) * 8)];
          const short8 kb1 = *(const short8*)&sK[cur][rowk * 64 + (((4 + lg) ^ (rowk & 7)) * 8)];
#pragma unroll
          for (int rg = 0; rg < 2; ++rg) {
            floatx4 acc = __builtin_amdgcn_mfma_f32_16x16x32_bf16(kb0, aq[rg][0], fzero4(), 0, 0, 0);
            s[rg][kt] = __builtin_amdgcn_mfma_f32_16x16x32_bf16(kb1, aq[rg][1], acc, 0, 0, 0);
          }
        }
        // ---- causal mask (diagonal steps only): kg = k0+kt*16+lg*4+r, qg = wq0+rg*16+li ----
        if (k0 + 63 > wq0) {
#pragma unroll
          for (int rg = 0; rg < 2; ++rg) {
            const int qg = wq0 + rg * 16 + li;
#pragma unroll
            for (int kt = 0; kt < 4; ++kt) {
              const int kgb = k0 + kt * 16 + lg * 4;
#pragma unroll
              for (int r = 0; r < 4; ++r)
                if (kgb + r > qg) s[rg][kt][r] = -1e30f;
            }
          }
        }
        // ---- in-lane row max + 2-lane-hop reduce (lanes li, li+16, li+32, li+48) ----
        float pm[2];
#pragma unroll
        for (int rg = 0; rg < 2; ++rg) {
          float m0_ = fmaxf(fmaxf(s[rg][0][0], s[rg][0][1]), fmaxf(s[rg][0][2], s[rg][0][3]));
          float m1_ = fmaxf(fmaxf(s[rg][1][0], s[rg][1][1]), fmaxf(s[rg][1][2], s[rg][1][3]));
          float m2_ = fmaxf(fmaxf(s[rg][2][0], s[rg][2][1]), fmaxf(s[rg][2][2], s[rg][2][3]));
          float m3_ = fmaxf(fmaxf(s[rg][3][0], s[rg][3][1]), fmaxf(s[rg][3][2], s[rg][3][3]));
          float p = fmaxf(fmaxf(m0_, m1_), fmaxf(m2_, m3_));
          p = fmaxf(p, __shfl_xor(p, 16));
          p = fmaxf(p, __shfl_xor(p, 32));
          pm[rg] = p;
        }
        // ---- defer-max: rescale only when max grew by > 8 somewhere in the wave ----
        const float need = fmaxf(pm[0] - m[0], pm[1] - m[1]);
        if (!__all(need <= 8.0f)) {
#pragma unroll
          for (int rg = 0; rg < 2; ++rg) {
            const float mn = fmaxf(m[rg], pm[rg]);
            const float a = __expf(m[rg] - mn);
            m[rg] = mn;
            lsum[rg] *= a;
            float ar[4];
#pragma unroll
            for (int r = 0; r < 4; ++r) ar[r] = __shfl(a, lg * 4 + r);
#pragma unroll
            for (int f = 0; f < 4; ++f) {
              o[rg][f][0] *= ar[0]; o[rg][f][1] *= ar[1];
              o[rg][f][2] *= ar[2]; o[rg][f][3] *= ar[3];
            }
          }
        }
        // ---- exp, partial lsum, packed P writes (row q = rg*16+li, col k) ----
#pragma unroll
        for (int rg = 0; rg < 2; ++rg) {
          const int rowb = (rg * 16 + li) * PSTR;
#pragma unroll
          for (int kt = 0; kt < 4; ++kt) {
            const float e0 = __expf(s[rg][kt][0] - m[rg]);
            const float e1 = __expf(s[rg][kt][1] - m[rg]);
            const float e2 = __expf(s[rg][kt][2] - m[rg]);
            const float e3 = __expf(s[rg][kt][3] - m[rg]);
            lsum[rg] += (e0 + e1) + (e2 + e3);
            unsigned* pp = (unsigned*)&pw[rowb + kt * 16 + lg * 4];
            pp[0] = pack2(e0, e1);
            pp[1] = pack2(e2, e3);
          }
        }
        // ---- P A-frags (same-wave LDS, in-order) ----
        short8 pa[2][2];
#pragma unroll
        for (int rg = 0; rg < 2; ++rg)
#pragma unroll
          for (int kc = 0; kc < 2; ++kc)
            pa[rg][kc] = *(const short8*)&pw[(rg * 16 + li) * PSTR + kc * 32 + lg * 8];
        // ---- PV: o[rg][f] += P @ V ----
#pragma unroll
        for (int f = 0; f < 4; ++f)
#pragma unroll
          for (int kc = 0; kc < 2; ++kc) {
            const int rowv = f * 16 + li;
            const short8 vb = *(const short8*)&sV[cur][rowv * 64 + (((kc * 4 + lg) ^ (rowv & 7)) * 8)];
            o[0][f] = __builtin_amdgcn_mfma_f32_16x16x32_bf16(pa[0][kc], vb, o[0][f], 0, 0, 0);
            o[1][f] = __builtin_amdgcn_mfma_f32_16x16x32_bf16(pa[1][kc], vb, o[1][f], 0, 0, 0);
          }
      }
      __syncthreads();
      cur ^= 1;
    }
    // ---- epilogue: finish lsum reduce, broadcast inv to o rows, write Y ----
#pragma unroll
    for (int rg = 0; rg < 2; ++rg) {
      float Ls = lsum[rg];
      Ls += __shfl_xor(Ls, 16);
      Ls += __shfl_xor(Ls, 32);
#pragma unroll
      for (int r = 0; r < 4; ++r) {
        const float inv = 1.0f / __shfl(Ls, lg * 4 + r);
        const int qg = wq0 + rg * 16 + lg * 4 + r;
        const size_t base = ((size_t)b * T_SEQ + qg) * 1024 + h * 64;
#pragma unroll
        for (int f = 0; f < 4; ++f)
          Y[base + f * 16 + li] = __float2bfloat16(o[rg][f][r] * inv);
      }
    }
  }
}

// ---------------- launch ----------------
extern "C" void kernel_launch(void* const* d_in, const int* in_sizes, int n_in,
                              void* d_out, int out_size, void* d_ws, size_t ws_size,
                              hipStream_t stream) {
  const float* x      = (const float*)d_in[0];
  const float* W_attn = (const float*)d_in[1];
  const float* b_attn = (const float*)d_in[2];
  const float* W_proj = (const float*)d_in[3];
  const float* b_proj = (const float*)d_in[4];
  float* out = (float*)d_out;

  char* ws = (char*)d_ws;
  bf16* Wt_a = (bf16*)(ws);
  bf16* Wt_p = (bf16*)(ws + 6291456);
  bf16* Qb   = (bf16*)(ws + 8388608);
  bf16* Kb   = (bf16*)(ws + 25165824);
  bf16* Vtb  = (bf16*)(ws + 41943040);
  bf16* x_bf = (bf16*)(ws + 58720256);
  bf16* Yb   = x_bf;  // alias: x_bf dead after GEMM1

  k_cast<<<4096, 256, 0, stream>>>(x, x_bf, 8388608);
  k_transpose<<<dim3(96, 32), dim3(32, 8), 0, stream>>>(W_attn, Wt_a, 1024, 3072);
  k_transpose<<<dim3(32, 32), dim3(32, 8), 0, stream>>>(W_proj, Wt_p, 1024, 1024);
  k_gemm<0><<<dim3(24, 64), 256, 0, stream>>>(x_bf, Wt_a, b_attn, Qb, Kb, Vtb,
                                              nullptr, 8192, 3072, 1024);
  k_attn<<<512, 256, 0, stream>>>(Qb, Kb, Vtb, Yb);
  k_gemm<1><<<dim3(8, 64), 256, 0, stream>>>(Yb, Wt_p, b_proj, nullptr, nullptr,
                                             nullptr, out, 8192, 1024, 1024);
}

// Round 8
// 240.685 us; speedup vs baseline: 2.4235x; 1.0037x over previous
//
#include <hip/hip_runtime.h>
#include <hip/hip_bf16.h>
#include <math.h>

typedef __attribute__((ext_vector_type(8))) short short8;
typedef __attribute__((ext_vector_type(4))) float floatx4;
using bf16 = __hip_bfloat16;

#define DEVI __device__ __forceinline__

DEVI floatx4 fzero4() { floatx4 z; z[0]=0.f; z[1]=0.f; z[2]=0.f; z[3]=0.f; return z; }

// hardware exp2: v_exp_f32 computes 2^x (ISA §3).  __exp2f doesn't exist on
// this toolchain (collides with glibc math.h); inline asm is exact + 1 inst.
DEVI float ex2(float x) {
  float r;
  asm("v_exp_f32 %0, %1" : "=v"(r) : "v"(x));
  return r;
}

DEVI unsigned short f2b(float x) {
  union { bf16 h; unsigned short u; } c;
  c.h = __float2bfloat16(x);
  return c.u;
}

DEVI unsigned pack2(float a, float b) {
  return (unsigned)f2b(a) | ((unsigned)f2b(b) << 16);
}

// async global->LDS, 16B per lane; lds dest must be wave-uniform base (+lane*16 implicit)
DEVI void gload16(const bf16* g, bf16* l) {
  typedef __attribute__((address_space(1))) const void gv_t;
  typedef __attribute__((address_space(3))) void lv_t;
  __builtin_amdgcn_global_load_lds((gv_t*)g, (lv_t*)l, 16, 0, 0);
}

// ---------------- cast f32 -> bf16 (8 elems/thread, vectorized) ----------------
__global__ __launch_bounds__(256) void k_cast(const float* __restrict__ in,
                                              bf16* __restrict__ out, int n) {
  int i = (blockIdx.x * 256 + threadIdx.x) * 8;
  if (i >= n) return;
  float4 a = *(const float4*)(in + i);
  float4 b = *(const float4*)(in + i + 4);
  short8 v;
  v[0] = (short)f2b(a.x); v[1] = (short)f2b(a.y);
  v[2] = (short)f2b(a.z); v[3] = (short)f2b(a.w);
  v[4] = (short)f2b(b.x); v[5] = (short)f2b(b.y);
  v[6] = (short)f2b(b.z); v[7] = (short)f2b(b.w);
  *(short8*)(out + i) = v;
}

// ---------------- transpose + cast: out[c][r] = in[r][c] ----------------
__global__ __launch_bounds__(256) void k_transpose(const float* __restrict__ in,
                                                   bf16* __restrict__ out,
                                                   int R, int C) {
  __shared__ float tile[32][33];
  int x = blockIdx.x * 32 + threadIdx.x;
  for (int i = threadIdx.y; i < 32; i += 8) {
    int y = blockIdx.y * 32 + i;
    tile[i][threadIdx.x] = (y < R && x < C) ? in[(size_t)y * C + x] : 0.f;
  }
  __syncthreads();
  int ox = blockIdx.y * 32 + threadIdx.x;
  for (int i = threadIdx.y; i < 32; i += 8) {
    int oy = blockIdx.x * 32 + i;
    if (oy < C && ox < R) out[(size_t)oy * R + ox] = __float2bfloat16(tile[threadIdx.x][i]);
  }
}

// ---------------- GEMM: C = A[M,K] @ Bt[N,K]^T + bias ----------------
// 128x128 tile, BK=32, 4 waves (2x2), global_load_lds staging (m97 structure).
// LDS tile = 4096 bf16 elements; rows 64-127 start at ELEMENT offset 2048.
template<int MODE>
__global__ __launch_bounds__(256) void k_gemm(
    const bf16* __restrict__ A, const bf16* __restrict__ Bt,
    const float* __restrict__ bias,
    bf16* __restrict__ Qo, bf16* __restrict__ Ko, bf16* __restrict__ Vo,
    float* __restrict__ Fo, int M, int N, int Kd) {
  __shared__ bf16 sA[128 * 32];
  __shared__ bf16 sB[128 * 32];
  const int tid = threadIdx.x;
  const int w = tid >> 6, l = tid & 63;
  const int lg = l >> 4, li = l & 15;
  const int wr = w >> 1, wc = w & 1;
  const int m0 = blockIdx.y * 128, n0 = blockIdx.x * 128;

  const int r0 = tid >> 2, ko0 = (tid & 3) * 8;
  const bf16* pa0 = A + (size_t)(m0 + r0) * Kd + ko0;
  const bf16* pa1 = A + (size_t)(m0 + 64 + r0) * Kd + ko0;
  const bf16* pb0 = Bt + (size_t)(n0 + r0) * Kd + ko0;
  const bf16* pb1 = Bt + (size_t)(n0 + 64 + r0) * Kd + ko0;

  floatx4 acc[4][4];
#pragma unroll
  for (int i = 0; i < 4; ++i)
#pragma unroll
    for (int j = 0; j < 4; ++j) acc[i][j] = fzero4();

  for (int k0 = 0; k0 < Kd; k0 += 32) {
    __syncthreads();
    gload16(pa0 + k0, sA + w * 512);
    gload16(pa1 + k0, sA + 2048 + w * 512);
    gload16(pb0 + k0, sB + w * 512);
    gload16(pb1 + k0, sB + 2048 + w * 512);
    __syncthreads();
    short8 af[4], bfr[4];
#pragma unroll
    for (int i = 0; i < 4; ++i)
      af[i] = *(const short8*)&sA[(wr * 64 + i * 16 + li) * 32 + lg * 8];
#pragma unroll
    for (int j = 0; j < 4; ++j)
      bfr[j] = *(const short8*)&sB[(wc * 64 + j * 16 + li) * 32 + lg * 8];
#pragma unroll
    for (int i = 0; i < 4; ++i)
#pragma unroll
      for (int j = 0; j < 4; ++j)
        acc[i][j] = __builtin_amdgcn_mfma_f32_16x16x32_bf16(af[i], bfr[j], acc[i][j], 0, 0, 0);
  }

  // epilogue: D frag mapping col = li, row = lg*4 + r  [m89/m91 verified]
  // MODE 0: Q pre-scaled by 1/8 * log2(e) so attention runs in exp2 domain.
#pragma unroll
  for (int i = 0; i < 4; ++i) {
#pragma unroll
    for (int j = 0; j < 4; ++j) {
      const int ng = n0 + wc * 64 + j * 16 + li;
      const float bs = bias[ng];
#pragma unroll
      for (int r = 0; r < 4; ++r) {
        const int mg = m0 + wr * 64 + i * 16 + lg * 4 + r;
        const float v = acc[i][j][r] + bs;
        if (MODE == 0) {
          const int bb = mg >> 11, t = mg & 2047;
          const int d = ng & 63;
          if (ng < 1024) {
            const int h = ng >> 6;
            Qo[(((size_t)bb * 16 + h) * 2048 + t) * 64 + d] = __float2bfloat16(v * 0.18033688011112042f);
          } else if (ng < 2048) {
            const int h = (ng - 1024) >> 6;
            Ko[(((size_t)bb * 16 + h) * 2048 + t) * 64 + d] = __float2bfloat16(v);
          } else {
            const int h = (ng - 2048) >> 6;
            Vo[(((size_t)bb * 16 + h) * 64 + d) * 2048 + t] = __float2bfloat16(v);
          }
        } else {
          Fo[(size_t)mg * N + ng] = v;
        }
      }
    }
  }
}

// ---------------- flash attention v4: fine grid + exp2 softmax ----------------
// 1024 blocks; block = 4 waves x 32 q-rows = one 128-row q-tile (nst = 2*tb+2
// steps of 64 keys).  Dispatch: xcd = bid&7 owns bh in [xcd*8, xcd*8+8); within
// an XCD, longest tiles (tb=15) dispatch first -> scheduler backfills short ones.
// Swapped mfma(K,Q): lane owns q-row li; in-lane softmax in exp2 domain (Q
// pre-scaled by log2e/8); defer-max THR=8 (log2) -> P <= 256.  K/V LDS
// double-buffered via gload16, XOR-swizzled chunks (round-3/5 verified).
#define T_SEQ 2048
#define PSTR 78

__global__ __launch_bounds__(256) void k_attn(
    const bf16* __restrict__ Q, const bf16* __restrict__ K,
    const bf16* __restrict__ Vt, bf16* __restrict__ Y) {
  __shared__ bf16 sK[2][64 * 64];
  __shared__ bf16 sV[2][64 * 64];
  __shared__ bf16 sP[4][32 * PSTR];

  const int tid = threadIdx.x;
  const int w = tid >> 6, l = tid & 63;
  const int lg = l >> 4, li = l & 15;
  const int bid = blockIdx.x;
  const int s = bid >> 3;
  const int bh = (bid & 7) * 8 + (s & 7);   // all 16 tiles of a head on one XCD
  const int tb = 15 - (s >> 3);             // big tiles dispatch first
  const int b = bh >> 4, h = bh & 15;

  const bf16* Qp = Q + (size_t)bh * (T_SEQ * 64);
  const bf16* Kp = K + (size_t)bh * (T_SEQ * 64);
  const bf16* Vp = Vt + (size_t)bh * (64 * T_SEQ);
  bf16* pw = &sP[w][0];

  const int q0 = tb * 128;
  const int wq0 = q0 + w * 32;
  const int nst = (q0 + 128) >> 6;

  // Q B-frags (swapped mfma): row q = wq0+rg*16+li, d-chunk dc*32+lg*8
  short8 aq[2][2];
#pragma unroll
  for (int rg = 0; rg < 2; ++rg)
#pragma unroll
    for (int dc = 0; dc < 2; ++dc)
      aq[rg][dc] = *(const short8*)(Qp + (size_t)(wq0 + rg * 16 + li) * 64 + dc * 32 + lg * 8);

  floatx4 o[2][4];
#pragma unroll
  for (int rg = 0; rg < 2; ++rg)
#pragma unroll
    for (int f = 0; f < 4; ++f) o[rg][f] = fzero4();
  float m[2] = {-INFINITY, -INFINITY};
  float lsum[2] = {0.f, 0.f};   // partial over this lane's 16-k groups

  auto STAGE = [&](int buf, int k0) {
#pragma unroll
    for (int half = 0; half < 2; ++half) {
      const int c = half * 256 + tid;
      const int row = c >> 3, cs = c & 7;
      const int sc = cs ^ (row & 7);
      bf16* kb = &sK[buf][(half * 256 + w * 64) * 8];
      bf16* vb = &sV[buf][(half * 256 + w * 64) * 8];
      gload16(Kp + (size_t)(k0 + row) * 64 + sc * 8, kb);
      gload16(Vp + (size_t)row * T_SEQ + k0 + sc * 8, vb);
    }
  };

  int cur = 0;
  STAGE(0, 0);
  __syncthreads();
  for (int t = 0; t < nst; ++t) {
    const int k0 = t << 6;
    if (t + 1 < nst) STAGE(cur ^ 1, k0 + 64);
    if (k0 <= wq0 + 31) {
      // ---- swapped QK^T: s[rg][kt]: lane holds q=li(+rg*16), k=kt*16+lg*4+r ----
      floatx4 s[2][4];
#pragma unroll
      for (int kt = 0; kt < 4; ++kt) {
        const int rowk = kt * 16 + li;
        const short8 kb0 = *(const short8*)&sK[cur][rowk * 64 + ((lg ^ (rowk & 7)) * 8)];
        const short8 kb1 = *(const short8*)&sK[cur][rowk * 64 + (((4 + lg) ^ (rowk & 7)) * 8)];
#pragma unroll
        for (int rg = 0; rg < 2; ++rg) {
          floatx4 acc = __builtin_amdgcn_mfma_f32_16x16x32_bf16(kb0, aq[rg][0], fzero4(), 0, 0, 0);
          s[rg][kt] = __builtin_amdgcn_mfma_f32_16x16x32_bf16(kb1, aq[rg][1], acc, 0, 0, 0);
        }
      }
      // ---- causal mask (diagonal steps only): kg = k0+kt*16+lg*4+r, qg = wq0+rg*16+li ----
      if (k0 + 63 > wq0) {
#pragma unroll
        for (int rg = 0; rg < 2; ++rg) {
          const int qg = wq0 + rg * 16 + li;
#pragma unroll
          for (int kt = 0; kt < 4; ++kt) {
            const int kgb = k0 + kt * 16 + lg * 4;
#pragma unroll
            for (int r = 0; r < 4; ++r)
              if (kgb + r > qg) s[rg][kt][r] = -1e30f;
          }
        }
      }
      // ---- in-lane row max + 2-lane-hop reduce (lanes li, li+16, li+32, li+48) ----
      float pm[2];
#pragma unroll
      for (int rg = 0; rg < 2; ++rg) {
        float m0_ = fmaxf(fmaxf(s[rg][0][0], s[rg][0][1]), fmaxf(s[rg][0][2], s[rg][0][3]));
        float m1_ = fmaxf(fmaxf(s[rg][1][0], s[rg][1][1]), fmaxf(s[rg][1][2], s[rg][1][3]));
        float m2_ = fmaxf(fmaxf(s[rg][2][0], s[rg][2][1]), fmaxf(s[rg][2][2], s[rg][2][3]));
        float m3_ = fmaxf(fmaxf(s[rg][3][0], s[rg][3][1]), fmaxf(s[rg][3][2], s[rg][3][3]));
        float p = fmaxf(fmaxf(m0_, m1_), fmaxf(m2_, m3_));
        p = fmaxf(p, __shfl_xor(p, 16));
        p = fmaxf(p, __shfl_xor(p, 32));
        pm[rg] = p;
      }
      // ---- defer-max: rescale only when max grew by > 8 (log2 units) ----
      const float need = fmaxf(pm[0] - m[0], pm[1] - m[1]);
      if (!__all(need <= 8.0f)) {
#pragma unroll
        for (int rg = 0; rg < 2; ++rg) {
          const float mn = fmaxf(m[rg], pm[rg]);
          const float a = ex2(m[rg] - mn);
          m[rg] = mn;
          lsum[rg] *= a;
          float ar[4];
#pragma unroll
          for (int r = 0; r < 4; ++r) ar[r] = __shfl(a, lg * 4 + r);
#pragma unroll
          for (int f = 0; f < 4; ++f) {
            o[rg][f][0] *= ar[0]; o[rg][f][1] *= ar[1];
            o[rg][f][2] *= ar[2]; o[rg][f][3] *= ar[3];
          }
        }
      }
      // ---- exp2, partial lsum, packed P writes (row q = rg*16+li, col k) ----
#pragma unroll
      for (int rg = 0; rg < 2; ++rg) {
        const int rowb = (rg * 16 + li) * PSTR;
#pragma unroll
        for (int kt = 0; kt < 4; ++kt) {
          const float e0 = ex2(s[rg][kt][0] - m[rg]);
          const float e1 = ex2(s[rg][kt][1] - m[rg]);
          const float e2 = ex2(s[rg][kt][2] - m[rg]);
          const float e3 = ex2(s[rg][kt][3] - m[rg]);
          lsum[rg] += (e0 + e1) + (e2 + e3);
          unsigned* pp = (unsigned*)&pw[rowb + kt * 16 + lg * 4];
          pp[0] = pack2(e0, e1);
          pp[1] = pack2(e2, e3);
        }
      }
      // ---- P A-frags (same-wave LDS, in-order) ----
      short8 pa[2][2];
#pragma unroll
      for (int rg = 0; rg < 2; ++rg)
#pragma unroll
        for (int kc = 0; kc < 2; ++kc)
          pa[rg][kc] = *(const short8*)&pw[(rg * 16 + li) * PSTR + kc * 32 + lg * 8];
      // ---- PV: o[rg][f] += P @ V ----
#pragma unroll
      for (int f = 0; f < 4; ++f)
#pragma unroll
        for (int kc = 0; kc < 2; ++kc) {
          const int rowv = f * 16 + li;
          const short8 vb = *(const short8*)&sV[cur][rowv * 64 + (((kc * 4 + lg) ^ (rowv & 7)) * 8)];
          o[0][f] = __builtin_amdgcn_mfma_f32_16x16x32_bf16(pa[0][kc], vb, o[0][f], 0, 0, 0);
          o[1][f] = __builtin_amdgcn_mfma_f32_16x16x32_bf16(pa[1][kc], vb, o[1][f], 0, 0, 0);
        }
    }
    __syncthreads();
    cur ^= 1;
  }
  // ---- epilogue: finish lsum reduce, broadcast inv to o rows, write Y ----
#pragma unroll
  for (int rg = 0; rg < 2; ++rg) {
    float Ls = lsum[rg];
    Ls += __shfl_xor(Ls, 16);
    Ls += __shfl_xor(Ls, 32);
#pragma unroll
    for (int r = 0; r < 4; ++r) {
      const float inv = 1.0f / __shfl(Ls, lg * 4 + r);
      const int qg = wq0 + rg * 16 + lg * 4 + r;
      const size_t base = ((size_t)b * T_SEQ + qg) * 1024 + h * 64;
#pragma unroll
      for (int f = 0; f < 4; ++f)
        Y[base + f * 16 + li] = __float2bfloat16(o[rg][f][r] * inv);
    }
  }
}

// ---------------- launch ----------------
extern "C" void kernel_launch(void* const* d_in, const int* in_sizes, int n_in,
                              void* d_out, int out_size, void* d_ws, size_t ws_size,
                              hipStream_t stream) {
  const float* x      = (const float*)d_in[0];
  const float* W_attn = (const float*)d_in[1];
  const float* b_attn = (const float*)d_in[2];
  const float* W_proj = (const float*)d_in[3];
  const float* b_proj = (const float*)d_in[4];
  float* out = (float*)d_out;

  char* ws = (char*)d_ws;
  bf16* Wt_a = (bf16*)(ws);
  bf16* Wt_p = (bf16*)(ws + 6291456);
  bf16* Qb   = (bf16*)(ws + 8388608);
  bf16* Kb   = (bf16*)(ws + 25165824);
  bf16* Vtb  = (bf16*)(ws + 41943040);
  bf16* x_bf = (bf16*)(ws + 58720256);
  bf16* Yb   = x_bf;  // alias: x_bf dead after GEMM1

  k_cast<<<4096, 256, 0, stream>>>(x, x_bf, 8388608);
  k_transpose<<<dim3(96, 32), dim3(32, 8), 0, stream>>>(W_attn, Wt_a, 1024, 3072);
  k_transpose<<<dim3(32, 32), dim3(32, 8), 0, stream>>>(W_proj, Wt_p, 1024, 1024);
  k_gemm<0><<<dim3(24, 64), 256, 0, stream>>>(x_bf, Wt_a, b_attn, Qb, Kb, Vtb,
                                              nullptr, 8192, 3072, 1024);
  k_attn<<<1024, 256, 0, stream>>>(Qb, Kb, Vtb, Yb);
  k_gemm<1><<<dim3(8, 64), 256, 0, stream>>>(Yb, Wt_p, b_proj, nullptr, nullptr,
                                             nullptr, out, 8192, 1024, 1024);
}

// Round 9
// 222.119 us; speedup vs baseline: 2.6261x; 1.0836x over previous
//
#include <hip/hip_runtime.h>
#include <hip/hip_bf16.h>
#include <math.h>

typedef __attribute__((ext_vector_type(8))) short short8;
typedef __attribute__((ext_vector_type(4))) short short4v;
typedef __attribute__((ext_vector_type(4))) float floatx4;
using bf16 = __hip_bfloat16;

#define DEVI __device__ __forceinline__

DEVI floatx4 fzero4() { floatx4 z; z[0]=0.f; z[1]=0.f; z[2]=0.f; z[3]=0.f; return z; }

// hardware exp2: v_exp_f32 computes 2^x (ISA §3).
DEVI float ex2(float x) {
  float r;
  asm("v_exp_f32 %0, %1" : "=v"(r) : "v"(x));
  return r;
}

DEVI unsigned short f2b(float x) {
  union { bf16 h; unsigned short u; } c;
  c.h = __float2bfloat16(x);
  return c.u;
}

// K=16 bf16 MFMA: A-frag = 4 bf16 at k=lg*4+j -- matches QK C/D output layout,
// so P feeds PV directly from registers (no LDS round-trip).
DEVI floatx4 mfma16(short4v a, short4v b, floatx4 c) {
#if __has_builtin(__builtin_amdgcn_mfma_f32_16x16x16bf16_1k)
  return __builtin_amdgcn_mfma_f32_16x16x16bf16_1k(a, b, c, 0, 0, 0);
#else
  floatx4 d;
  asm("v_mfma_f32_16x16x16_bf16 %0, %1, %2, %3" : "=v"(d) : "v"(a), "v"(b), "v"(c));
  return d;
#endif
}

// async global->LDS, 16B per lane; lds dest must be wave-uniform base (+lane*16 implicit)
DEVI void gload16(const bf16* g, bf16* l) {
  typedef __attribute__((address_space(1))) const void gv_t;
  typedef __attribute__((address_space(3))) void lv_t;
  __builtin_amdgcn_global_load_lds((gv_t*)g, (lv_t*)l, 16, 0, 0);
}

// ---------------- cast f32 -> bf16 (8 elems/thread, vectorized) ----------------
__global__ __launch_bounds__(256) void k_cast(const float* __restrict__ in,
                                              bf16* __restrict__ out, int n) {
  int i = (blockIdx.x * 256 + threadIdx.x) * 8;
  if (i >= n) return;
  float4 a = *(const float4*)(in + i);
  float4 b = *(const float4*)(in + i + 4);
  short8 v;
  v[0] = (short)f2b(a.x); v[1] = (short)f2b(a.y);
  v[2] = (short)f2b(a.z); v[3] = (short)f2b(a.w);
  v[4] = (short)f2b(b.x); v[5] = (short)f2b(b.y);
  v[6] = (short)f2b(b.z); v[7] = (short)f2b(b.w);
  *(short8*)(out + i) = v;
}

// ---------------- transpose + cast: out[c][r] = in[r][c] ----------------
__global__ __launch_bounds__(256) void k_transpose(const float* __restrict__ in,
                                                   bf16* __restrict__ out,
                                                   int R, int C) {
  __shared__ float tile[32][33];
  int x = blockIdx.x * 32 + threadIdx.x;
  for (int i = threadIdx.y; i < 32; i += 8) {
    int y = blockIdx.y * 32 + i;
    tile[i][threadIdx.x] = (y < R && x < C) ? in[(size_t)y * C + x] : 0.f;
  }
  __syncthreads();
  int ox = blockIdx.y * 32 + threadIdx.x;
  for (int i = threadIdx.y; i < 32; i += 8) {
    int oy = blockIdx.x * 32 + i;
    if (oy < C && ox < R) out[(size_t)oy * R + ox] = __float2bfloat16(tile[threadIdx.x][i]);
  }
}

// ---------------- GEMM: C = A[M,K] @ Bt[N,K]^T + bias ----------------
// 128x128 tile, BK=32, 4 waves (2x2), global_load_lds staging (m97 structure).
template<int MODE>
__global__ __launch_bounds__(256) void k_gemm(
    const bf16* __restrict__ A, const bf16* __restrict__ Bt,
    const float* __restrict__ bias,
    bf16* __restrict__ Qo, bf16* __restrict__ Ko, bf16* __restrict__ Vo,
    float* __restrict__ Fo, int M, int N, int Kd) {
  __shared__ bf16 sA[128 * 32];
  __shared__ bf16 sB[128 * 32];
  const int tid = threadIdx.x;
  const int w = tid >> 6, l = tid & 63;
  const int lg = l >> 4, li = l & 15;
  const int wr = w >> 1, wc = w & 1;
  const int m0 = blockIdx.y * 128, n0 = blockIdx.x * 128;

  const int r0 = tid >> 2, ko0 = (tid & 3) * 8;
  const bf16* pa0 = A + (size_t)(m0 + r0) * Kd + ko0;
  const bf16* pa1 = A + (size_t)(m0 + 64 + r0) * Kd + ko0;
  const bf16* pb0 = Bt + (size_t)(n0 + r0) * Kd + ko0;
  const bf16* pb1 = Bt + (size_t)(n0 + 64 + r0) * Kd + ko0;

  floatx4 acc[4][4];
#pragma unroll
  for (int i = 0; i < 4; ++i)
#pragma unroll
    for (int j = 0; j < 4; ++j) acc[i][j] = fzero4();

  for (int k0 = 0; k0 < Kd; k0 += 32) {
    __syncthreads();
    gload16(pa0 + k0, sA + w * 512);
    gload16(pa1 + k0, sA + 2048 + w * 512);
    gload16(pb0 + k0, sB + w * 512);
    gload16(pb1 + k0, sB + 2048 + w * 512);
    __syncthreads();
    short8 af[4], bfr[4];
#pragma unroll
    for (int i = 0; i < 4; ++i)
      af[i] = *(const short8*)&sA[(wr * 64 + i * 16 + li) * 32 + lg * 8];
#pragma unroll
    for (int j = 0; j < 4; ++j)
      bfr[j] = *(const short8*)&sB[(wc * 64 + j * 16 + li) * 32 + lg * 8];
#pragma unroll
    for (int i = 0; i < 4; ++i)
#pragma unroll
      for (int j = 0; j < 4; ++j)
        acc[i][j] = __builtin_amdgcn_mfma_f32_16x16x32_bf16(af[i], bfr[j], acc[i][j], 0, 0, 0);
  }

  // epilogue: D frag mapping col = li, row = lg*4 + r  [m89/m91 verified]
  // MODE 0: Q pre-scaled by 1/8 * log2(e) so attention runs in exp2 domain.
#pragma unroll
  for (int i = 0; i < 4; ++i) {
#pragma unroll
    for (int j = 0; j < 4; ++j) {
      const int ng = n0 + wc * 64 + j * 16 + li;
      const float bs = bias[ng];
#pragma unroll
      for (int r = 0; r < 4; ++r) {
        const int mg = m0 + wr * 64 + i * 16 + lg * 4 + r;
        const float v = acc[i][j][r] + bs;
        if (MODE == 0) {
          const int bb = mg >> 11, t = mg & 2047;
          const int d = ng & 63;
          if (ng < 1024) {
            const int h = ng >> 6;
            Qo[(((size_t)bb * 16 + h) * 2048 + t) * 64 + d] = __float2bfloat16(v * 0.18033688011112042f);
          } else if (ng < 2048) {
            const int h = (ng - 1024) >> 6;
            Ko[(((size_t)bb * 16 + h) * 2048 + t) * 64 + d] = __float2bfloat16(v);
          } else {
            const int h = (ng - 2048) >> 6;
            Vo[(((size_t)bb * 16 + h) * 64 + d) * 2048 + t] = __float2bfloat16(v);
          }
        } else {
          Fo[(size_t)mg * N + ng] = v;
        }
      }
    }
  }
}

// ---------------- flash attention v5: register-resident P via K=16 PV ----------------
// 1024 blocks; block = 4 waves x 32 q-rows = one 128-row q-tile.  Swapped
// mfma(K,Q) puts P at k=kt*16+lg*4+r per lane == the 16x16x16 A-frag layout,
// so PV runs as 4x mfma16 per d-block straight from registers: no sP buffer.
// LDS = K/V dbuf only (32.9KB) -> 4 blocks/CU resident.  exp2-domain softmax,
// defer-max THR=8.  K/V staged via gload16 with XOR-swizzled chunks.
#define T_SEQ 2048

__global__ __launch_bounds__(256) void k_attn(
    const bf16* __restrict__ Q, const bf16* __restrict__ K,
    const bf16* __restrict__ Vt, bf16* __restrict__ Y) {
  __shared__ bf16 sK[2][64 * 64];
  __shared__ bf16 sV[2][64 * 64];

  const int tid = threadIdx.x;
  const int w = tid >> 6, l = tid & 63;
  const int lg = l >> 4, li = l & 15;
  const int bid = blockIdx.x;
  const int s = bid >> 3;
  const int bh = (bid & 7) * 8 + (s & 7);   // all 16 tiles of a head on one XCD
  const int tb = 15 - (s >> 3);             // big tiles dispatch first
  const int b = bh >> 4, h = bh & 15;

  const bf16* Qp = Q + (size_t)bh * (T_SEQ * 64);
  const bf16* Kp = K + (size_t)bh * (T_SEQ * 64);
  const bf16* Vp = Vt + (size_t)bh * (64 * T_SEQ);

  const int q0 = tb * 128;
  const int wq0 = q0 + w * 32;
  const int nst = (q0 + 128) >> 6;

  // Q B-frags (swapped mfma): row q = wq0+rg*16+li, d-chunk dc*32+lg*8
  short8 aq[2][2];
#pragma unroll
  for (int rg = 0; rg < 2; ++rg)
#pragma unroll
    for (int dc = 0; dc < 2; ++dc)
      aq[rg][dc] = *(const short8*)(Qp + (size_t)(wq0 + rg * 16 + li) * 64 + dc * 32 + lg * 8);

  floatx4 o[2][4];
#pragma unroll
  for (int rg = 0; rg < 2; ++rg)
#pragma unroll
    for (int f = 0; f < 4; ++f) o[rg][f] = fzero4();
  float m[2] = {-INFINITY, -INFINITY};
  float lsum[2] = {0.f, 0.f};   // partial over this lane's 16-k groups

  auto STAGE = [&](int buf, int k0) {
#pragma unroll
    for (int half = 0; half < 2; ++half) {
      const int c = half * 256 + tid;
      const int row = c >> 3, cs = c & 7;
      const int sc = cs ^ (row & 7);
      bf16* kb = &sK[buf][(half * 256 + w * 64) * 8];
      bf16* vb = &sV[buf][(half * 256 + w * 64) * 8];
      gload16(Kp + (size_t)(k0 + row) * 64 + sc * 8, kb);
      gload16(Vp + (size_t)row * T_SEQ + k0 + sc * 8, vb);
    }
  };

  int cur = 0;
  STAGE(0, 0);
  __syncthreads();
  for (int t = 0; t < nst; ++t) {
    const int k0 = t << 6;
    if (t + 1 < nst) STAGE(cur ^ 1, k0 + 64);
    if (k0 <= wq0 + 31) {
      // ---- swapped QK^T: s[rg][kt]: lane holds q=li(+rg*16), k=kt*16+lg*4+r ----
      floatx4 s[2][4];
#pragma unroll
      for (int kt = 0; kt < 4; ++kt) {
        const int rowk = kt * 16 + li;
        const short8 kb0 = *(const short8*)&sK[cur][rowk * 64 + ((lg ^ (rowk & 7)) * 8)];
        const short8 kb1 = *(const short8*)&sK[cur][rowk * 64 + (((4 + lg) ^ (rowk & 7)) * 8)];
#pragma unroll
        for (int rg = 0; rg < 2; ++rg) {
          floatx4 acc = __builtin_amdgcn_mfma_f32_16x16x32_bf16(kb0, aq[rg][0], fzero4(), 0, 0, 0);
          s[rg][kt] = __builtin_amdgcn_mfma_f32_16x16x32_bf16(kb1, aq[rg][1], acc, 0, 0, 0);
        }
      }
      // ---- causal mask (diagonal steps only) ----
      if (k0 + 63 > wq0) {
#pragma unroll
        for (int rg = 0; rg < 2; ++rg) {
          const int qg = wq0 + rg * 16 + li;
#pragma unroll
          for (int kt = 0; kt < 4; ++kt) {
            const int kgb = k0 + kt * 16 + lg * 4;
#pragma unroll
            for (int r = 0; r < 4; ++r)
              if (kgb + r > qg) s[rg][kt][r] = -1e30f;
          }
        }
      }
      // ---- in-lane row max + 2-hop reduce (lanes li, li+16, li+32, li+48) ----
      float pm[2];
#pragma unroll
      for (int rg = 0; rg < 2; ++rg) {
        float m0_ = fmaxf(fmaxf(s[rg][0][0], s[rg][0][1]), fmaxf(s[rg][0][2], s[rg][0][3]));
        float m1_ = fmaxf(fmaxf(s[rg][1][0], s[rg][1][1]), fmaxf(s[rg][1][2], s[rg][1][3]));
        float m2_ = fmaxf(fmaxf(s[rg][2][0], s[rg][2][1]), fmaxf(s[rg][2][2], s[rg][2][3]));
        float m3_ = fmaxf(fmaxf(s[rg][3][0], s[rg][3][1]), fmaxf(s[rg][3][2], s[rg][3][3]));
        float p = fmaxf(fmaxf(m0_, m1_), fmaxf(m2_, m3_));
        p = fmaxf(p, __shfl_xor(p, 16));
        p = fmaxf(p, __shfl_xor(p, 32));
        pm[rg] = p;
      }
      // ---- defer-max: rescale only when max grew by > 8 (log2 units) ----
      const float need = fmaxf(pm[0] - m[0], pm[1] - m[1]);
      if (!__all(need <= 8.0f)) {
#pragma unroll
        for (int rg = 0; rg < 2; ++rg) {
          const float mn = fmaxf(m[rg], pm[rg]);
          const float a = ex2(m[rg] - mn);
          m[rg] = mn;
          lsum[rg] *= a;
          float ar[4];
#pragma unroll
          for (int r = 0; r < 4; ++r) ar[r] = __shfl(a, lg * 4 + r);
#pragma unroll
          for (int f = 0; f < 4; ++f) {
            o[rg][f][0] *= ar[0]; o[rg][f][1] *= ar[1];
            o[rg][f][2] *= ar[2]; o[rg][f][3] *= ar[3];
          }
        }
      }
      // ---- exp2 -> P stays in registers as K=16 A-frags (k = kt*16+lg*4+r) ----
      short4v pa4[2][4];
#pragma unroll
      for (int rg = 0; rg < 2; ++rg) {
#pragma unroll
        for (int kt = 0; kt < 4; ++kt) {
          const float e0 = ex2(s[rg][kt][0] - m[rg]);
          const float e1 = ex2(s[rg][kt][1] - m[rg]);
          const float e2 = ex2(s[rg][kt][2] - m[rg]);
          const float e3 = ex2(s[rg][kt][3] - m[rg]);
          lsum[rg] += (e0 + e1) + (e2 + e3);
          short4v pv;
          pv[0] = (short)f2b(e0); pv[1] = (short)f2b(e1);
          pv[2] = (short)f2b(e2); pv[3] = (short)f2b(e3);
          pa4[rg][kt] = pv;
        }
      }
      // ---- PV: o[rg][f] += P @ V via 4x mfma16 per d-block (register A-frags) ----
      // V B-frag (K=16): col d=f*16+li, k = kt*16+lg*4+j -> 8B from sV [d][k] row
      // (16B-chunk cc=2kt+(lg>>1) XOR row-swizzled, half (lg&1)).
#pragma unroll
      for (int f = 0; f < 4; ++f) {
        const int rowv = f * 16 + li;
        const int rx = rowv & 7;
#pragma unroll
        for (int kt = 0; kt < 4; ++kt) {
          const int cc = 2 * kt + (lg >> 1);
          const short4v vb4 = *(const short4v*)&sV[cur][rowv * 64 + (((cc ^ rx) << 3) | ((lg & 1) << 2))];
          o[0][f] = mfma16(pa4[0][kt], vb4, o[0][f]);
          o[1][f] = mfma16(pa4[1][kt], vb4, o[1][f]);
        }
      }
    }
    __syncthreads();
    cur ^= 1;
  }
  // ---- epilogue: finish lsum reduce, broadcast inv to o rows, write Y ----
#pragma unroll
  for (int rg = 0; rg < 2; ++rg) {
    float Ls = lsum[rg];
    Ls += __shfl_xor(Ls, 16);
    Ls += __shfl_xor(Ls, 32);
#pragma unroll
    for (int r = 0; r < 4; ++r) {
      const float inv = 1.0f / __shfl(Ls, lg * 4 + r);
      const int qg = wq0 + rg * 16 + lg * 4 + r;
      const size_t base = ((size_t)b * T_SEQ + qg) * 1024 + h * 64;
#pragma unroll
      for (int f = 0; f < 4; ++f)
        Y[base + f * 16 + li] = __float2bfloat16(o[rg][f][r] * inv);
    }
  }
}

// ---------------- launch ----------------
extern "C" void kernel_launch(void* const* d_in, const int* in_sizes, int n_in,
                              void* d_out, int out_size, void* d_ws, size_t ws_size,
                              hipStream_t stream) {
  const float* x      = (const float*)d_in[0];
  const float* W_attn = (const float*)d_in[1];
  const float* b_attn = (const float*)d_in[2];
  const float* W_proj = (const float*)d_in[3];
  const float* b_proj = (const float*)d_in[4];
  float* out = (float*)d_out;

  char* ws = (char*)d_ws;
  bf16* Wt_a = (bf16*)(ws);
  bf16* Wt_p = (bf16*)(ws + 6291456);
  bf16* Qb   = (bf16*)(ws + 8388608);
  bf16* Kb   = (bf16*)(ws + 25165824);
  bf16* Vtb  = (bf16*)(ws + 41943040);
  bf16* x_bf = (bf16*)(ws + 58720256);
  bf16* Yb   = x_bf;  // alias: x_bf dead after GEMM1

  k_cast<<<4096, 256, 0, stream>>>(x, x_bf, 8388608);
  k_transpose<<<dim3(96, 32), dim3(32, 8), 0, stream>>>(W_attn, Wt_a, 1024, 3072);
  k_transpose<<<dim3(32, 32), dim3(32, 8), 0, stream>>>(W_proj, Wt_p, 1024, 1024);
  k_gemm<0><<<dim3(24, 64), 256, 0, stream>>>(x_bf, Wt_a, b_attn, Qb, Kb, Vtb,
                                              nullptr, 8192, 3072, 1024);
  k_attn<<<1024, 256, 0, stream>>>(Qb, Kb, Vtb, Yb);
  k_gemm<1><<<dim3(8, 64), 256, 0, stream>>>(Yb, Wt_p, b_proj, nullptr, nullptr,
                                             nullptr, out, 8192, 1024, 1024);
}

// Round 10
// 199.949 us; speedup vs baseline: 2.9172x; 1.1109x over previous
//
#include <hip/hip_runtime.h>
#include <hip/hip_bf16.h>
#include <math.h>

typedef __attribute__((ext_vector_type(8))) short short8;
typedef __attribute__((ext_vector_type(4))) short short4v;
typedef __attribute__((ext_vector_type(4))) float floatx4;
using bf16 = __hip_bfloat16;

#define DEVI __device__ __forceinline__

DEVI floatx4 fzero4() { floatx4 z; z[0]=0.f; z[1]=0.f; z[2]=0.f; z[3]=0.f; return z; }

// hardware exp2: v_exp_f32 computes 2^x (ISA §3).
DEVI float ex2(float x) {
  float r;
  asm("v_exp_f32 %0, %1" : "=v"(r) : "v"(x));
  return r;
}

DEVI unsigned short f2b(float x) {
  union { bf16 h; unsigned short u; } c;
  c.h = __float2bfloat16(x);
  return c.u;
}

// K=16 bf16 MFMA: A-frag = 4 bf16 at k=lg*4+j -- matches QK C/D output layout,
// so P feeds PV directly from registers (no LDS round-trip).
DEVI floatx4 mfma16(short4v a, short4v b, floatx4 c) {
#if __has_builtin(__builtin_amdgcn_mfma_f32_16x16x16bf16_1k)
  return __builtin_amdgcn_mfma_f32_16x16x16bf16_1k(a, b, c, 0, 0, 0);
#else
  floatx4 d;
  asm("v_mfma_f32_16x16x16_bf16 %0, %1, %2, %3" : "=v"(d) : "v"(a), "v"(b), "v"(c));
  return d;
#endif
}

// async global->LDS, 16B per lane; lds dest must be wave-uniform base (+lane*16 implicit)
DEVI void gload16(const bf16* g, bf16* l) {
  typedef __attribute__((address_space(1))) const void gv_t;
  typedef __attribute__((address_space(3))) void lv_t;
  __builtin_amdgcn_global_load_lds((gv_t*)g, (lv_t*)l, 16, 0, 0);
}

// ---------------- cast f32 -> bf16 (8 elems/thread, vectorized) ----------------
__global__ __launch_bounds__(256) void k_cast(const float* __restrict__ in,
                                              bf16* __restrict__ out, int n) {
  int i = (blockIdx.x * 256 + threadIdx.x) * 8;
  if (i >= n) return;
  float4 a = *(const float4*)(in + i);
  float4 b = *(const float4*)(in + i + 4);
  short8 v;
  v[0] = (short)f2b(a.x); v[1] = (short)f2b(a.y);
  v[2] = (short)f2b(a.z); v[3] = (short)f2b(a.w);
  v[4] = (short)f2b(b.x); v[5] = (short)f2b(b.y);
  v[6] = (short)f2b(b.z); v[7] = (short)f2b(b.w);
  *(short8*)(out + i) = v;
}

// ---------------- transpose + cast: out[c][r] = in[r][c] ----------------
__global__ __launch_bounds__(256) void k_transpose(const float* __restrict__ in,
                                                   bf16* __restrict__ out,
                                                   int R, int C) {
  __shared__ float tile[32][33];
  int x = blockIdx.x * 32 + threadIdx.x;
  for (int i = threadIdx.y; i < 32; i += 8) {
    int y = blockIdx.y * 32 + i;
    tile[i][threadIdx.x] = (y < R && x < C) ? in[(size_t)y * C + x] : 0.f;
  }
  __syncthreads();
  int ox = blockIdx.y * 32 + threadIdx.x;
  for (int i = threadIdx.y; i < 32; i += 8) {
    int oy = blockIdx.x * 32 + i;
    if (oy < C && ox < R) out[(size_t)oy * R + ox] = __float2bfloat16(tile[threadIdx.x][i]);
  }
}

// ---------------- GEMM v2: C = A[M,K] @ Bt[N,K]^T + bias ----------------
// 128x128 tile, BK=32, 4 waves (2x2).  Double-buffered global_load_lds staging
// with counted vmcnt(4): prefetch of tile k+1 stays in flight across the
// barrier while tile k computes (T3/T4 minimum 2-phase recipe).  Raw s_barrier
// (NOT __syncthreads, which drains vmcnt(0) and kills the pipeline).
// Grid is 1D (nbx*64 blocks); XCD-bijective swizzle: xcd=bid&7 owns m-tiles
// [xcd*8,xcd*8+8), n-outer m-inner -> per-XCD L2 set = 2MB A-stripe + 256KB Bt.
template<int MODE>
__global__ __launch_bounds__(256) void k_gemm(
    const bf16* __restrict__ A, const bf16* __restrict__ Bt,
    const float* __restrict__ bias,
    bf16* __restrict__ Qo, bf16* __restrict__ Ko, bf16* __restrict__ Vo,
    float* __restrict__ Fo, int M, int N, int Kd) {
  __shared__ bf16 sA[2][128 * 32];
  __shared__ bf16 sB[2][128 * 32];
  const int tid = threadIdx.x;
  const int w = tid >> 6, l = tid & 63;
  const int lg = l >> 4, li = l & 15;
  const int wr = w >> 1, wc = w & 1;
  // XCD swizzle (requires nby==64, true for both GEMMs):
  const int ii = blockIdx.x >> 3, xcd = blockIdx.x & 7;
  const int bx = ii >> 3, by = xcd * 8 + (ii & 7);
  const int m0 = by * 128, n0 = bx * 128;

  const int r0 = tid >> 2, ko0 = (tid & 3) * 8;
  const bf16* pa0 = A + (size_t)(m0 + r0) * Kd + ko0;
  const bf16* pa1 = A + (size_t)(m0 + 64 + r0) * Kd + ko0;
  const bf16* pb0 = Bt + (size_t)(n0 + r0) * Kd + ko0;
  const bf16* pb1 = Bt + (size_t)(n0 + 64 + r0) * Kd + ko0;

  floatx4 acc[4][4];
#pragma unroll
  for (int i = 0; i < 4; ++i)
#pragma unroll
    for (int j = 0; j < 4; ++j) acc[i][j] = fzero4();

  // stage tile (4 gload_lds per thread = 16KB for the block)
  auto STAGE = [&](int buf, int k0) {
    gload16(pa0 + k0, &sA[buf][w * 512]);
    gload16(pa1 + k0, &sA[buf][2048 + w * 512]);
    gload16(pb0 + k0, &sB[buf][w * 512]);
    gload16(pb1 + k0, &sB[buf][2048 + w * 512]);
  };

  STAGE(0, 0);
  int cur = 0;
  for (int k0 = 0; k0 < Kd; k0 += 32) {
    if (k0 + 32 < Kd) {
      STAGE(cur ^ 1, k0 + 32);                       // prefetch flies across barrier
      asm volatile("s_waitcnt vmcnt(4)" ::: "memory");  // my tile-k loads landed
    } else {
      asm volatile("s_waitcnt vmcnt(0)" ::: "memory");  // last tile: drain
    }
    __builtin_amdgcn_s_barrier();                     // all waves' tile-k landed
    short8 af[4], bfr[4];
#pragma unroll
    for (int i = 0; i < 4; ++i)
      af[i] = *(const short8*)&sA[cur][(wr * 64 + i * 16 + li) * 32 + lg * 8];
#pragma unroll
    for (int j = 0; j < 4; ++j)
      bfr[j] = *(const short8*)&sB[cur][(wc * 64 + j * 16 + li) * 32 + lg * 8];
#pragma unroll
    for (int i = 0; i < 4; ++i)
#pragma unroll
      for (int j = 0; j < 4; ++j)
        acc[i][j] = __builtin_amdgcn_mfma_f32_16x16x32_bf16(af[i], bfr[j], acc[i][j], 0, 0, 0);
    __builtin_amdgcn_s_barrier();                     // all waves done reading buf[cur]
    cur ^= 1;
  }

  // epilogue: D frag mapping col = li, row = lg*4 + r  [m89/m91 verified]
  // MODE 0: Q pre-scaled by 1/8 * log2(e) so attention runs in exp2 domain.
#pragma unroll
  for (int i = 0; i < 4; ++i) {
#pragma unroll
    for (int j = 0; j < 4; ++j) {
      const int ng = n0 + wc * 64 + j * 16 + li;
      const float bs = bias[ng];
#pragma unroll
      for (int r = 0; r < 4; ++r) {
        const int mg = m0 + wr * 64 + i * 16 + lg * 4 + r;
        const float v = acc[i][j][r] + bs;
        if (MODE == 0) {
          const int bb = mg >> 11, t = mg & 2047;
          const int d = ng & 63;
          if (ng < 1024) {
            const int h = ng >> 6;
            Qo[(((size_t)bb * 16 + h) * 2048 + t) * 64 + d] = __float2bfloat16(v * 0.18033688011112042f);
          } else if (ng < 2048) {
            const int h = (ng - 1024) >> 6;
            Ko[(((size_t)bb * 16 + h) * 2048 + t) * 64 + d] = __float2bfloat16(v);
          } else {
            const int h = (ng - 2048) >> 6;
            Vo[(((size_t)bb * 16 + h) * 64 + d) * 2048 + t] = __float2bfloat16(v);
          }
        } else {
          Fo[(size_t)mg * N + ng] = v;
        }
      }
    }
  }
}

// ---------------- flash attention v5: register-resident P via K=16 PV ----------------
// (unchanged from round 9: 222 µs total, attn ~85 µs)
#define T_SEQ 2048

__global__ __launch_bounds__(256) void k_attn(
    const bf16* __restrict__ Q, const bf16* __restrict__ K,
    const bf16* __restrict__ Vt, bf16* __restrict__ Y) {
  __shared__ bf16 sK[2][64 * 64];
  __shared__ bf16 sV[2][64 * 64];

  const int tid = threadIdx.x;
  const int w = tid >> 6, l = tid & 63;
  const int lg = l >> 4, li = l & 15;
  const int bid = blockIdx.x;
  const int s = bid >> 3;
  const int bh = (bid & 7) * 8 + (s & 7);   // all 16 tiles of a head on one XCD
  const int tb = 15 - (s >> 3);             // big tiles dispatch first
  const int b = bh >> 4, h = bh & 15;

  const bf16* Qp = Q + (size_t)bh * (T_SEQ * 64);
  const bf16* Kp = K + (size_t)bh * (T_SEQ * 64);
  const bf16* Vp = Vt + (size_t)bh * (64 * T_SEQ);

  const int q0 = tb * 128;
  const int wq0 = q0 + w * 32;
  const int nst = (q0 + 128) >> 6;

  // Q B-frags (swapped mfma): row q = wq0+rg*16+li, d-chunk dc*32+lg*8
  short8 aq[2][2];
#pragma unroll
  for (int rg = 0; rg < 2; ++rg)
#pragma unroll
    for (int dc = 0; dc < 2; ++dc)
      aq[rg][dc] = *(const short8*)(Qp + (size_t)(wq0 + rg * 16 + li) * 64 + dc * 32 + lg * 8);

  floatx4 o[2][4];
#pragma unroll
  for (int rg = 0; rg < 2; ++rg)
#pragma unroll
    for (int f = 0; f < 4; ++f) o[rg][f] = fzero4();
  float m[2] = {-INFINITY, -INFINITY};
  float lsum[2] = {0.f, 0.f};   // partial over this lane's 16-k groups

  auto STAGE = [&](int buf, int k0) {
#pragma unroll
    for (int half = 0; half < 2; ++half) {
      const int c = half * 256 + tid;
      const int row = c >> 3, cs = c & 7;
      const int sc = cs ^ (row & 7);
      bf16* kb = &sK[buf][(half * 256 + w * 64) * 8];
      bf16* vb = &sV[buf][(half * 256 + w * 64) * 8];
      gload16(Kp + (size_t)(k0 + row) * 64 + sc * 8, kb);
      gload16(Vp + (size_t)row * T_SEQ + k0 + sc * 8, vb);
    }
  };

  int cur = 0;
  STAGE(0, 0);
  __syncthreads();
  for (int t = 0; t < nst; ++t) {
    const int k0 = t << 6;
    if (t + 1 < nst) STAGE(cur ^ 1, k0 + 64);
    if (k0 <= wq0 + 31) {
      // ---- swapped QK^T: s[rg][kt]: lane holds q=li(+rg*16), k=kt*16+lg*4+r ----
      floatx4 s[2][4];
#pragma unroll
      for (int kt = 0; kt < 4; ++kt) {
        const int rowk = kt * 16 + li;
        const short8 kb0 = *(const short8*)&sK[cur][rowk * 64 + ((lg ^ (rowk & 7)) * 8)];
        const short8 kb1 = *(const short8*)&sK[cur][rowk * 64 + (((4 + lg) ^ (rowk & 7)) * 8)];
#pragma unroll
        for (int rg = 0; rg < 2; ++rg) {
          floatx4 acc = __builtin_amdgcn_mfma_f32_16x16x32_bf16(kb0, aq[rg][0], fzero4(), 0, 0, 0);
          s[rg][kt] = __builtin_amdgcn_mfma_f32_16x16x32_bf16(kb1, aq[rg][1], acc, 0, 0, 0);
        }
      }
      // ---- causal mask (diagonal steps only) ----
      if (k0 + 63 > wq0) {
#pragma unroll
        for (int rg = 0; rg < 2; ++rg) {
          const int qg = wq0 + rg * 16 + li;
#pragma unroll
          for (int kt = 0; kt < 4; ++kt) {
            const int kgb = k0 + kt * 16 + lg * 4;
#pragma unroll
            for (int r = 0; r < 4; ++r)
              if (kgb + r > qg) s[rg][kt][r] = -1e30f;
          }
        }
      }
      // ---- in-lane row max + 2-hop reduce (lanes li, li+16, li+32, li+48) ----
      float pm[2];
#pragma unroll
      for (int rg = 0; rg < 2; ++rg) {
        float m0_ = fmaxf(fmaxf(s[rg][0][0], s[rg][0][1]), fmaxf(s[rg][0][2], s[rg][0][3]));
        float m1_ = fmaxf(fmaxf(s[rg][1][0], s[rg][1][1]), fmaxf(s[rg][1][2], s[rg][1][3]));
        float m2_ = fmaxf(fmaxf(s[rg][2][0], s[rg][2][1]), fmaxf(s[rg][2][2], s[rg][2][3]));
        float m3_ = fmaxf(fmaxf(s[rg][3][0], s[rg][3][1]), fmaxf(s[rg][3][2], s[rg][3][3]));
        float p = fmaxf(fmaxf(m0_, m1_), fmaxf(m2_, m3_));
        p = fmaxf(p, __shfl_xor(p, 16));
        p = fmaxf(p, __shfl_xor(p, 32));
        pm[rg] = p;
      }
      // ---- defer-max: rescale only when max grew by > 8 (log2 units) ----
      const float need = fmaxf(pm[0] - m[0], pm[1] - m[1]);
      if (!__all(need <= 8.0f)) {
#pragma unroll
        for (int rg = 0; rg < 2; ++rg) {
          const float mn = fmaxf(m[rg], pm[rg]);
          const float a = ex2(m[rg] - mn);
          m[rg] = mn;
          lsum[rg] *= a;
          float ar[4];
#pragma unroll
          for (int r = 0; r < 4; ++r) ar[r] = __shfl(a, lg * 4 + r);
#pragma unroll
          for (int f = 0; f < 4; ++f) {
            o[rg][f][0] *= ar[0]; o[rg][f][1] *= ar[1];
            o[rg][f][2] *= ar[2]; o[rg][f][3] *= ar[3];
          }
        }
      }
      // ---- exp2 -> P stays in registers as K=16 A-frags (k = kt*16+lg*4+r) ----
      short4v pa4[2][4];
#pragma unroll
      for (int rg = 0; rg < 2; ++rg) {
#pragma unroll
        for (int kt = 0; kt < 4; ++kt) {
          const float e0 = ex2(s[rg][kt][0] - m[rg]);
          const float e1 = ex2(s[rg][kt][1] - m[rg]);
          const float e2 = ex2(s[rg][kt][2] - m[rg]);
          const float e3 = ex2(s[rg][kt][3] - m[rg]);
          lsum[rg] += (e0 + e1) + (e2 + e3);
          short4v pv;
          pv[0] = (short)f2b(e0); pv[1] = (short)f2b(e1);
          pv[2] = (short)f2b(e2); pv[3] = (short)f2b(e3);
          pa4[rg][kt] = pv;
        }
      }
      // ---- PV: o[rg][f] += P @ V via 4x mfma16 per d-block (register A-frags) ----
#pragma unroll
      for (int f = 0; f < 4; ++f) {
        const int rowv = f * 16 + li;
        const int rx = rowv & 7;
#pragma unroll
        for (int kt = 0; kt < 4; ++kt) {
          const int cc = 2 * kt + (lg >> 1);
          const short4v vb4 = *(const short4v*)&sV[cur][rowv * 64 + (((cc ^ rx) << 3) | ((lg & 1) << 2))];
          o[0][f] = mfma16(pa4[0][kt], vb4, o[0][f]);
          o[1][f] = mfma16(pa4[1][kt], vb4, o[1][f]);
        }
      }
    }
    __syncthreads();
    cur ^= 1;
  }
  // ---- epilogue: finish lsum reduce, broadcast inv to o rows, write Y ----
#pragma unroll
  for (int rg = 0; rg < 2; ++rg) {
    float Ls = lsum[rg];
    Ls += __shfl_xor(Ls, 16);
    Ls += __shfl_xor(Ls, 32);
#pragma unroll
    for (int r = 0; r < 4; ++r) {
      const float inv = 1.0f / __shfl(Ls, lg * 4 + r);
      const int qg = wq0 + rg * 16 + lg * 4 + r;
      const size_t base = ((size_t)b * T_SEQ + qg) * 1024 + h * 64;
#pragma unroll
      for (int f = 0; f < 4; ++f)
        Y[base + f * 16 + li] = __float2bfloat16(o[rg][f][r] * inv);
    }
  }
}

// ---------------- launch ----------------
extern "C" void kernel_launch(void* const* d_in, const int* in_sizes, int n_in,
                              void* d_out, int out_size, void* d_ws, size_t ws_size,
                              hipStream_t stream) {
  const float* x      = (const float*)d_in[0];
  const float* W_attn = (const float*)d_in[1];
  const float* b_attn = (const float*)d_in[2];
  const float* W_proj = (const float*)d_in[3];
  const float* b_proj = (const float*)d_in[4];
  float* out = (float*)d_out;

  char* ws = (char*)d_ws;
  bf16* Wt_a = (bf16*)(ws);
  bf16* Wt_p = (bf16*)(ws + 6291456);
  bf16* Qb   = (bf16*)(ws + 8388608);
  bf16* Kb   = (bf16*)(ws + 25165824);
  bf16* Vtb  = (bf16*)(ws + 41943040);
  bf16* x_bf = (bf16*)(ws + 58720256);
  bf16* Yb   = x_bf;  // alias: x_bf dead after GEMM1

  k_cast<<<4096, 256, 0, stream>>>(x, x_bf, 8388608);
  k_transpose<<<dim3(96, 32), dim3(32, 8), 0, stream>>>(W_attn, Wt_a, 1024, 3072);
  k_transpose<<<dim3(32, 32), dim3(32, 8), 0, stream>>>(W_proj, Wt_p, 1024, 1024);
  // 1D grids, XCD-swizzled inside: GEMM1 24x64=1536 blocks, GEMM2 8x64=512.
  k_gemm<0><<<1536, 256, 0, stream>>>(x_bf, Wt_a, b_attn, Qb, Kb, Vtb,
                                      nullptr, 8192, 3072, 1024);
  k_attn<<<1024, 256, 0, stream>>>(Qb, Kb, Vtb, Yb);
  k_gemm<1><<<512, 256, 0, stream>>>(Yb, Wt_p, b_proj, nullptr, nullptr,
                                     nullptr, out, 8192, 1024, 1024);
}

// Round 11
// 198.996 us; speedup vs baseline: 2.9312x; 1.0048x over previous
//
#include <hip/hip_runtime.h>
#include <hip/hip_bf16.h>
#include <math.h>

typedef __attribute__((ext_vector_type(8))) short short8;
typedef __attribute__((ext_vector_type(4))) short short4v;
typedef __attribute__((ext_vector_type(4))) float floatx4;
using bf16 = __hip_bfloat16;

#define DEVI __device__ __forceinline__

DEVI floatx4 fzero4() { floatx4 z; z[0]=0.f; z[1]=0.f; z[2]=0.f; z[3]=0.f; return z; }

// hardware exp2: v_exp_f32 computes 2^x (ISA §3).
DEVI float ex2(float x) {
  float r;
  asm("v_exp_f32 %0, %1" : "=v"(r) : "v"(x));
  return r;
}

DEVI unsigned short f2b(float x) {
  union { bf16 h; unsigned short u; } c;
  c.h = __float2bfloat16(x);
  return c.u;
}

// K=16 bf16 MFMA: A-frag = 4 bf16 at k=lg*4+j -- matches QK C/D output layout,
// so P feeds PV directly from registers (no LDS round-trip).
DEVI floatx4 mfma16(short4v a, short4v b, floatx4 c) {
#if __has_builtin(__builtin_amdgcn_mfma_f32_16x16x16bf16_1k)
  return __builtin_amdgcn_mfma_f32_16x16x16bf16_1k(a, b, c, 0, 0, 0);
#else
  floatx4 d;
  asm("v_mfma_f32_16x16x16_bf16 %0, %1, %2, %3" : "=v"(d) : "v"(a), "v"(b), "v"(c));
  return d;
#endif
}

// async global->LDS, 16B per lane; lds dest must be wave-uniform base (+lane*16 implicit)
DEVI void gload16(const bf16* g, bf16* l) {
  typedef __attribute__((address_space(1))) const void gv_t;
  typedef __attribute__((address_space(3))) void lv_t;
  __builtin_amdgcn_global_load_lds((gv_t*)g, (lv_t*)l, 16, 0, 0);
}

// ---------------- cast f32 -> bf16 (8 elems/thread, vectorized) ----------------
__global__ __launch_bounds__(256) void k_cast(const float* __restrict__ in,
                                              bf16* __restrict__ out, int n) {
  int i = (blockIdx.x * 256 + threadIdx.x) * 8;
  if (i >= n) return;
  float4 a = *(const float4*)(in + i);
  float4 b = *(const float4*)(in + i + 4);
  short8 v;
  v[0] = (short)f2b(a.x); v[1] = (short)f2b(a.y);
  v[2] = (short)f2b(a.z); v[3] = (short)f2b(a.w);
  v[4] = (short)f2b(b.x); v[5] = (short)f2b(b.y);
  v[6] = (short)f2b(b.z); v[7] = (short)f2b(b.w);
  *(short8*)(out + i) = v;
}

// ---------------- transpose + cast: out[c][r] = in[r][c] ----------------
__global__ __launch_bounds__(256) void k_transpose(const float* __restrict__ in,
                                                   bf16* __restrict__ out,
                                                   int R, int C) {
  __shared__ float tile[32][33];
  int x = blockIdx.x * 32 + threadIdx.x;
  for (int i = threadIdx.y; i < 32; i += 8) {
    int y = blockIdx.y * 32 + i;
    tile[i][threadIdx.x] = (y < R && x < C) ? in[(size_t)y * C + x] : 0.f;
  }
  __syncthreads();
  int ox = blockIdx.y * 32 + threadIdx.x;
  for (int i = threadIdx.y; i < 32; i += 8) {
    int oy = blockIdx.x * 32 + i;
    if (oy < C && ox < R) out[(size_t)oy * R + ox] = __float2bfloat16(tile[threadIdx.x][i]);
  }
}

// ---------------- GEMM v2: C = A[M,K] @ Bt[N,K]^T + bias ----------------
// 128x128 tile, BK=32, 4 waves (2x2).  Double-buffered global_load_lds staging
// with counted vmcnt(4); raw s_barrier (round-10 verified, -~15 µs on GEMM1).
// XCD-bijective swizzle: xcd=bid&7 owns m-tiles [xcd*8,xcd*8+8).
template<int MODE>
__global__ __launch_bounds__(256) void k_gemm(
    const bf16* __restrict__ A, const bf16* __restrict__ Bt,
    const float* __restrict__ bias,
    bf16* __restrict__ Qo, bf16* __restrict__ Ko, bf16* __restrict__ Vo,
    float* __restrict__ Fo, int M, int N, int Kd) {
  __shared__ bf16 sA[2][128 * 32];
  __shared__ bf16 sB[2][128 * 32];
  const int tid = threadIdx.x;
  const int w = tid >> 6, l = tid & 63;
  const int lg = l >> 4, li = l & 15;
  const int wr = w >> 1, wc = w & 1;
  const int ii = blockIdx.x >> 3, xcd = blockIdx.x & 7;
  const int bx = ii >> 3, by = xcd * 8 + (ii & 7);
  const int m0 = by * 128, n0 = bx * 128;

  const int r0 = tid >> 2, ko0 = (tid & 3) * 8;
  const bf16* pa0 = A + (size_t)(m0 + r0) * Kd + ko0;
  const bf16* pa1 = A + (size_t)(m0 + 64 + r0) * Kd + ko0;
  const bf16* pb0 = Bt + (size_t)(n0 + r0) * Kd + ko0;
  const bf16* pb1 = Bt + (size_t)(n0 + 64 + r0) * Kd + ko0;

  floatx4 acc[4][4];
#pragma unroll
  for (int i = 0; i < 4; ++i)
#pragma unroll
    for (int j = 0; j < 4; ++j) acc[i][j] = fzero4();

  auto STAGE = [&](int buf, int k0) {
    gload16(pa0 + k0, &sA[buf][w * 512]);
    gload16(pa1 + k0, &sA[buf][2048 + w * 512]);
    gload16(pb0 + k0, &sB[buf][w * 512]);
    gload16(pb1 + k0, &sB[buf][2048 + w * 512]);
  };

  STAGE(0, 0);
  int cur = 0;
  for (int k0 = 0; k0 < Kd; k0 += 32) {
    if (k0 + 32 < Kd) {
      STAGE(cur ^ 1, k0 + 32);
      asm volatile("s_waitcnt vmcnt(4)" ::: "memory");
    } else {
      asm volatile("s_waitcnt vmcnt(0)" ::: "memory");
    }
    __builtin_amdgcn_s_barrier();
    short8 af[4], bfr[4];
#pragma unroll
    for (int i = 0; i < 4; ++i)
      af[i] = *(const short8*)&sA[cur][(wr * 64 + i * 16 + li) * 32 + lg * 8];
#pragma unroll
    for (int j = 0; j < 4; ++j)
      bfr[j] = *(const short8*)&sB[cur][(wc * 64 + j * 16 + li) * 32 + lg * 8];
#pragma unroll
    for (int i = 0; i < 4; ++i)
#pragma unroll
      for (int j = 0; j < 4; ++j)
        acc[i][j] = __builtin_amdgcn_mfma_f32_16x16x32_bf16(af[i], bfr[j], acc[i][j], 0, 0, 0);
    __builtin_amdgcn_s_barrier();
    cur ^= 1;
  }

  // epilogue: D frag mapping col = li, row = lg*4 + r  [m89/m91 verified]
  // MODE 0: Q pre-scaled by 1/8 * log2(e) so attention runs in exp2 domain.
#pragma unroll
  for (int i = 0; i < 4; ++i) {
#pragma unroll
    for (int j = 0; j < 4; ++j) {
      const int ng = n0 + wc * 64 + j * 16 + li;
      const float bs = bias[ng];
#pragma unroll
      for (int r = 0; r < 4; ++r) {
        const int mg = m0 + wr * 64 + i * 16 + lg * 4 + r;
        const float v = acc[i][j][r] + bs;
        if (MODE == 0) {
          const int bb = mg >> 11, t = mg & 2047;
          const int d = ng & 63;
          if (ng < 1024) {
            const int h = ng >> 6;
            Qo[(((size_t)bb * 16 + h) * 2048 + t) * 64 + d] = __float2bfloat16(v * 0.18033688011112042f);
          } else if (ng < 2048) {
            const int h = (ng - 1024) >> 6;
            Ko[(((size_t)bb * 16 + h) * 2048 + t) * 64 + d] = __float2bfloat16(v);
          } else {
            const int h = (ng - 2048) >> 6;
            Vo[(((size_t)bb * 16 + h) * 64 + d) * 2048 + t] = __float2bfloat16(v);
          }
        } else {
          Fo[(size_t)mg * N + ng] = v;
        }
      }
    }
  }
}

// ---------------- flash attention v6: counted-vmcnt pipelined K/V staging ----------------
// v5 + T4 fix: the loop-end __syncthreads() drained vmcnt(0), exposing the
// prefetch latency every step.  Now: STAGE(next); vmcnt(4) (only prev step's
// 4 loads must land, new 4 stay in flight); s_barrier; compute; s_barrier.
#define T_SEQ 2048

__global__ __launch_bounds__(256) void k_attn(
    const bf16* __restrict__ Q, const bf16* __restrict__ K,
    const bf16* __restrict__ Vt, bf16* __restrict__ Y) {
  __shared__ bf16 sK[2][64 * 64];
  __shared__ bf16 sV[2][64 * 64];

  const int tid = threadIdx.x;
  const int w = tid >> 6, l = tid & 63;
  const int lg = l >> 4, li = l & 15;
  const int bid = blockIdx.x;
  const int s = bid >> 3;
  const int bh = (bid & 7) * 8 + (s & 7);   // all 16 tiles of a head on one XCD
  const int tb = 15 - (s >> 3);             // big tiles dispatch first
  const int b = bh >> 4, h = bh & 15;

  const bf16* Qp = Q + (size_t)bh * (T_SEQ * 64);
  const bf16* Kp = K + (size_t)bh * (T_SEQ * 64);
  const bf16* Vp = Vt + (size_t)bh * (64 * T_SEQ);

  const int q0 = tb * 128;
  const int wq0 = q0 + w * 32;
  const int nst = (q0 + 128) >> 6;

  // Q B-frags (swapped mfma): row q = wq0+rg*16+li, d-chunk dc*32+lg*8
  short8 aq[2][2];
#pragma unroll
  for (int rg = 0; rg < 2; ++rg)
#pragma unroll
    for (int dc = 0; dc < 2; ++dc)
      aq[rg][dc] = *(const short8*)(Qp + (size_t)(wq0 + rg * 16 + li) * 64 + dc * 32 + lg * 8);

  floatx4 o[2][4];
#pragma unroll
  for (int rg = 0; rg < 2; ++rg)
#pragma unroll
    for (int f = 0; f < 4; ++f) o[rg][f] = fzero4();
  float m[2] = {-INFINITY, -INFINITY};
  float lsum[2] = {0.f, 0.f};   // partial over this lane's 16-k groups

  auto STAGE = [&](int buf, int k0) {
#pragma unroll
    for (int half = 0; half < 2; ++half) {
      const int c = half * 256 + tid;
      const int row = c >> 3, cs = c & 7;
      const int sc = cs ^ (row & 7);
      bf16* kb = &sK[buf][(half * 256 + w * 64) * 8];
      bf16* vb = &sV[buf][(half * 256 + w * 64) * 8];
      gload16(Kp + (size_t)(k0 + row) * 64 + sc * 8, kb);
      gload16(Vp + (size_t)row * T_SEQ + k0 + sc * 8, vb);
    }
  };

  int cur = 0;
  STAGE(0, 0);
  for (int t = 0; t < nst; ++t) {
    const int k0 = t << 6;
    if (t + 1 < nst) {
      STAGE(cur ^ 1, k0 + 64);                          // prefetch stays in flight
      asm volatile("s_waitcnt vmcnt(4)" ::: "memory");  // tile-t loads landed
    } else {
      asm volatile("s_waitcnt vmcnt(0)" ::: "memory");  // last tile: drain
    }
    __builtin_amdgcn_s_barrier();                       // all waves' tile-t landed
    if (k0 <= wq0 + 31) {
      // ---- swapped QK^T: s[rg][kt]: lane holds q=li(+rg*16), k=kt*16+lg*4+r ----
      floatx4 s[2][4];
#pragma unroll
      for (int kt = 0; kt < 4; ++kt) {
        const int rowk = kt * 16 + li;
        const short8 kb0 = *(const short8*)&sK[cur][rowk * 64 + ((lg ^ (rowk & 7)) * 8)];
        const short8 kb1 = *(const short8*)&sK[cur][rowk * 64 + (((4 + lg) ^ (rowk & 7)) * 8)];
#pragma unroll
        for (int rg = 0; rg < 2; ++rg) {
          floatx4 acc = __builtin_amdgcn_mfma_f32_16x16x32_bf16(kb0, aq[rg][0], fzero4(), 0, 0, 0);
          s[rg][kt] = __builtin_amdgcn_mfma_f32_16x16x32_bf16(kb1, aq[rg][1], acc, 0, 0, 0);
        }
      }
      // ---- causal mask (diagonal steps only) ----
      if (k0 + 63 > wq0) {
#pragma unroll
        for (int rg = 0; rg < 2; ++rg) {
          const int qg = wq0 + rg * 16 + li;
#pragma unroll
          for (int kt = 0; kt < 4; ++kt) {
            const int kgb = k0 + kt * 16 + lg * 4;
#pragma unroll
            for (int r = 0; r < 4; ++r)
              if (kgb + r > qg) s[rg][kt][r] = -1e30f;
          }
        }
      }
      // ---- in-lane row max + 2-hop reduce (lanes li, li+16, li+32, li+48) ----
      float pm[2];
#pragma unroll
      for (int rg = 0; rg < 2; ++rg) {
        float m0_ = fmaxf(fmaxf(s[rg][0][0], s[rg][0][1]), fmaxf(s[rg][0][2], s[rg][0][3]));
        float m1_ = fmaxf(fmaxf(s[rg][1][0], s[rg][1][1]), fmaxf(s[rg][1][2], s[rg][1][3]));
        float m2_ = fmaxf(fmaxf(s[rg][2][0], s[rg][2][1]), fmaxf(s[rg][2][2], s[rg][2][3]));
        float m3_ = fmaxf(fmaxf(s[rg][3][0], s[rg][3][1]), fmaxf(s[rg][3][2], s[rg][3][3]));
        float p = fmaxf(fmaxf(m0_, m1_), fmaxf(m2_, m3_));
        p = fmaxf(p, __shfl_xor(p, 16));
        p = fmaxf(p, __shfl_xor(p, 32));
        pm[rg] = p;
      }
      // ---- defer-max: rescale only when max grew by > 8 (log2 units) ----
      const float need = fmaxf(pm[0] - m[0], pm[1] - m[1]);
      if (!__all(need <= 8.0f)) {
#pragma unroll
        for (int rg = 0; rg < 2; ++rg) {
          const float mn = fmaxf(m[rg], pm[rg]);
          const float a = ex2(m[rg] - mn);
          m[rg] = mn;
          lsum[rg] *= a;
          float ar[4];
#pragma unroll
          for (int r = 0; r < 4; ++r) ar[r] = __shfl(a, lg * 4 + r);
#pragma unroll
          for (int f = 0; f < 4; ++f) {
            o[rg][f][0] *= ar[0]; o[rg][f][1] *= ar[1];
            o[rg][f][2] *= ar[2]; o[rg][f][3] *= ar[3];
          }
        }
      }
      // ---- exp2 -> P stays in registers as K=16 A-frags (k = kt*16+lg*4+r) ----
      short4v pa4[2][4];
#pragma unroll
      for (int rg = 0; rg < 2; ++rg) {
#pragma unroll
        for (int kt = 0; kt < 4; ++kt) {
          const float e0 = ex2(s[rg][kt][0] - m[rg]);
          const float e1 = ex2(s[rg][kt][1] - m[rg]);
          const float e2 = ex2(s[rg][kt][2] - m[rg]);
          const float e3 = ex2(s[rg][kt][3] - m[rg]);
          lsum[rg] += (e0 + e1) + (e2 + e3);
          short4v pv;
          pv[0] = (short)f2b(e0); pv[1] = (short)f2b(e1);
          pv[2] = (short)f2b(e2); pv[3] = (short)f2b(e3);
          pa4[rg][kt] = pv;
        }
      }
      // ---- PV: o[rg][f] += P @ V via 4x mfma16 per d-block (register A-frags) ----
#pragma unroll
      for (int f = 0; f < 4; ++f) {
        const int rowv = f * 16 + li;
        const int rx = rowv & 7;
#pragma unroll
        for (int kt = 0; kt < 4; ++kt) {
          const int cc = 2 * kt + (lg >> 1);
          const short4v vb4 = *(const short4v*)&sV[cur][rowv * 64 + (((cc ^ rx) << 3) | ((lg & 1) << 2))];
          o[0][f] = mfma16(pa4[0][kt], vb4, o[0][f]);
          o[1][f] = mfma16(pa4[1][kt], vb4, o[1][f]);
        }
      }
    }
    __builtin_amdgcn_s_barrier();                       // all waves done reading buf[cur]
    cur ^= 1;
  }
  // ---- epilogue: finish lsum reduce, broadcast inv to o rows, write Y ----
#pragma unroll
  for (int rg = 0; rg < 2; ++rg) {
    float Ls = lsum[rg];
    Ls += __shfl_xor(Ls, 16);
    Ls += __shfl_xor(Ls, 32);
#pragma unroll
    for (int r = 0; r < 4; ++r) {
      const float inv = 1.0f / __shfl(Ls, lg * 4 + r);
      const int qg = wq0 + rg * 16 + lg * 4 + r;
      const size_t base = ((size_t)b * T_SEQ + qg) * 1024 + h * 64;
#pragma unroll
      for (int f = 0; f < 4; ++f)
        Y[base + f * 16 + li] = __float2bfloat16(o[rg][f][r] * inv);
    }
  }
}

// ---------------- launch ----------------
extern "C" void kernel_launch(void* const* d_in, const int* in_sizes, int n_in,
                              void* d_out, int out_size, void* d_ws, size_t ws_size,
                              hipStream_t stream) {
  const float* x      = (const float*)d_in[0];
  const float* W_attn = (const float*)d_in[1];
  const float* b_attn = (const float*)d_in[2];
  const float* W_proj = (const float*)d_in[3];
  const float* b_proj = (const float*)d_in[4];
  float* out = (float*)d_out;

  char* ws = (char*)d_ws;
  bf16* Wt_a = (bf16*)(ws);
  bf16* Wt_p = (bf16*)(ws + 6291456);
  bf16* Qb   = (bf16*)(ws + 8388608);
  bf16* Kb   = (bf16*)(ws + 25165824);
  bf16* Vtb  = (bf16*)(ws + 41943040);
  bf16* x_bf = (bf16*)(ws + 58720256);
  bf16* Yb   = x_bf;  // alias: x_bf dead after GEMM1

  k_cast<<<4096, 256, 0, stream>>>(x, x_bf, 8388608);
  k_transpose<<<dim3(96, 32), dim3(32, 8), 0, stream>>>(W_attn, Wt_a, 1024, 3072);
  k_transpose<<<dim3(32, 32), dim3(32, 8), 0, stream>>>(W_proj, Wt_p, 1024, 1024);
  // 1D grids, XCD-swizzled inside: GEMM1 24x64=1536 blocks, GEMM2 8x64=512.
  k_gemm<0><<<1536, 256, 0, stream>>>(x_bf, Wt_a, b_attn, Qb, Kb, Vtb,
                                      nullptr, 8192, 3072, 1024);
  k_attn<<<1024, 256, 0, stream>>>(Qb, Kb, Vtb, Yb);
  k_gemm<1><<<512, 256, 0, stream>>>(Yb, Wt_p, b_proj, nullptr, nullptr,
                                     nullptr, out, 8192, 1024, 1024);
}

// Round 12
// 189.513 us; speedup vs baseline: 3.0779x; 1.0500x over previous
//
#include <hip/hip_runtime.h>
#include <hip/hip_bf16.h>
#include <math.h>

typedef __attribute__((ext_vector_type(8))) short short8;
typedef __attribute__((ext_vector_type(4))) short short4v;
typedef __attribute__((ext_vector_type(4))) float floatx4;
using bf16 = __hip_bfloat16;

#define DEVI __device__ __forceinline__

DEVI floatx4 fzero4() { floatx4 z; z[0]=0.f; z[1]=0.f; z[2]=0.f; z[3]=0.f; return z; }

// hardware exp2: v_exp_f32 computes 2^x (ISA §3).
DEVI float ex2(float x) {
  float r;
  asm("v_exp_f32 %0, %1" : "=v"(r) : "v"(x));
  return r;
}

// 3-input max, single VOP3 inst (T17).
DEVI float max3f(float a, float b, float c) {
  float d;
  asm("v_max3_f32 %0, %1, %2, %3" : "=v"(d) : "v"(a), "v"(b), "v"(c));
  return d;
}

DEVI unsigned short f2b(float x) {
  union { bf16 h; unsigned short u; } c;
  c.h = __float2bfloat16(x);
  return c.u;
}

// K=16 bf16 MFMA: A-frag = 4 bf16 at k=lg*4+j -- matches QK C/D output layout,
// so P feeds PV directly from registers (no LDS round-trip).
DEVI floatx4 mfma16(short4v a, short4v b, floatx4 c) {
#if __has_builtin(__builtin_amdgcn_mfma_f32_16x16x16bf16_1k)
  return __builtin_amdgcn_mfma_f32_16x16x16bf16_1k(a, b, c, 0, 0, 0);
#else
  floatx4 d;
  asm("v_mfma_f32_16x16x16_bf16 %0, %1, %2, %3" : "=v"(d) : "v"(a), "v"(b), "v"(c));
  return d;
#endif
}

// async global->LDS, 16B per lane; lds dest must be wave-uniform base (+lane*16 implicit)
DEVI void gload16(const bf16* g, bf16* l) {
  typedef __attribute__((address_space(1))) const void gv_t;
  typedef __attribute__((address_space(3))) void lv_t;
  __builtin_amdgcn_global_load_lds((gv_t*)g, (lv_t*)l, 16, 0, 0);
}

// ---------------- cast f32 -> bf16 (8 elems/thread, vectorized) ----------------
__global__ __launch_bounds__(256) void k_cast(const float* __restrict__ in,
                                              bf16* __restrict__ out, int n) {
  int i = (blockIdx.x * 256 + threadIdx.x) * 8;
  if (i >= n) return;
  float4 a = *(const float4*)(in + i);
  float4 b = *(const float4*)(in + i + 4);
  short8 v;
  v[0] = (short)f2b(a.x); v[1] = (short)f2b(a.y);
  v[2] = (short)f2b(a.z); v[3] = (short)f2b(a.w);
  v[4] = (short)f2b(b.x); v[5] = (short)f2b(b.y);
  v[6] = (short)f2b(b.z); v[7] = (short)f2b(b.w);
  *(short8*)(out + i) = v;
}

// ---------------- transpose + cast: out[c][r] = in[r][c] ----------------
__global__ __launch_bounds__(256) void k_transpose(const float* __restrict__ in,
                                                   bf16* __restrict__ out,
                                                   int R, int C) {
  __shared__ float tile[32][33];
  int x = blockIdx.x * 32 + threadIdx.x;
  for (int i = threadIdx.y; i < 32; i += 8) {
    int y = blockIdx.y * 32 + i;
    tile[i][threadIdx.x] = (y < R && x < C) ? in[(size_t)y * C + x] : 0.f;
  }
  __syncthreads();
  int ox = blockIdx.y * 32 + threadIdx.x;
  for (int i = threadIdx.y; i < 32; i += 8) {
    int oy = blockIdx.x * 32 + i;
    if (oy < C && ox < R) out[(size_t)oy * R + ox] = __float2bfloat16(tile[threadIdx.x][i]);
  }
}

// ---------------- GEMM v2: C = A[M,K] @ Bt[N,K]^T + bias ----------------
// 128x128 tile, BK=32, 4 waves (2x2).  Double-buffered global_load_lds staging
// with counted vmcnt(4); raw s_barrier (round-10 verified).
// XCD-bijective swizzle: xcd=bid&7 owns m-tiles [xcd*8,xcd*8+8).
template<int MODE>
__global__ __launch_bounds__(256) void k_gemm(
    const bf16* __restrict__ A, const bf16* __restrict__ Bt,
    const float* __restrict__ bias,
    bf16* __restrict__ Qo, bf16* __restrict__ Ko, bf16* __restrict__ Vo,
    float* __restrict__ Fo, int M, int N, int Kd) {
  __shared__ bf16 sA[2][128 * 32];
  __shared__ bf16 sB[2][128 * 32];
  const int tid = threadIdx.x;
  const int w = tid >> 6, l = tid & 63;
  const int lg = l >> 4, li = l & 15;
  const int wr = w >> 1, wc = w & 1;
  const int ii = blockIdx.x >> 3, xcd = blockIdx.x & 7;
  const int bx = ii >> 3, by = xcd * 8 + (ii & 7);
  const int m0 = by * 128, n0 = bx * 128;

  const int r0 = tid >> 2, ko0 = (tid & 3) * 8;
  const bf16* pa0 = A + (size_t)(m0 + r0) * Kd + ko0;
  const bf16* pa1 = A + (size_t)(m0 + 64 + r0) * Kd + ko0;
  const bf16* pb0 = Bt + (size_t)(n0 + r0) * Kd + ko0;
  const bf16* pb1 = Bt + (size_t)(n0 + 64 + r0) * Kd + ko0;

  floatx4 acc[4][4];
#pragma unroll
  for (int i = 0; i < 4; ++i)
#pragma unroll
    for (int j = 0; j < 4; ++j) acc[i][j] = fzero4();

  auto STAGE = [&](int buf, int k0) {
    gload16(pa0 + k0, &sA[buf][w * 512]);
    gload16(pa1 + k0, &sA[buf][2048 + w * 512]);
    gload16(pb0 + k0, &sB[buf][w * 512]);
    gload16(pb1 + k0, &sB[buf][2048 + w * 512]);
  };

  STAGE(0, 0);
  int cur = 0;
  for (int k0 = 0; k0 < Kd; k0 += 32) {
    if (k0 + 32 < Kd) {
      STAGE(cur ^ 1, k0 + 32);
      asm volatile("s_waitcnt vmcnt(4)" ::: "memory");
    } else {
      asm volatile("s_waitcnt vmcnt(0)" ::: "memory");
    }
    __builtin_amdgcn_s_barrier();
    short8 af[4], bfr[4];
#pragma unroll
    for (int i = 0; i < 4; ++i)
      af[i] = *(const short8*)&sA[cur][(wr * 64 + i * 16 + li) * 32 + lg * 8];
#pragma unroll
    for (int j = 0; j < 4; ++j)
      bfr[j] = *(const short8*)&sB[cur][(wc * 64 + j * 16 + li) * 32 + lg * 8];
#pragma unroll
    for (int i = 0; i < 4; ++i)
#pragma unroll
      for (int j = 0; j < 4; ++j)
        acc[i][j] = __builtin_amdgcn_mfma_f32_16x16x32_bf16(af[i], bfr[j], acc[i][j], 0, 0, 0);
    __builtin_amdgcn_s_barrier();
    cur ^= 1;
  }

  // epilogue: D frag mapping col = li, row = lg*4 + r  [m89/m91 verified]
  // MODE 0: Q pre-scaled by 1/8 * log2(e) so attention runs in exp2 domain.
  // V stores vectorized short4 along t (r=0..3 consecutive t, bb constant).
#pragma unroll
  for (int i = 0; i < 4; ++i) {
#pragma unroll
    for (int j = 0; j < 4; ++j) {
      const int ng = n0 + wc * 64 + j * 16 + li;
      const float bs = bias[ng];
      const int mgb = m0 + wr * 64 + i * 16 + lg * 4;
      if (MODE == 0) {
        const int bb = mgb >> 11, t = mgb & 2047;
        const int d = ng & 63;
        if (ng < 1024) {
          const int h = ng >> 6;
#pragma unroll
          for (int r = 0; r < 4; ++r)
            Qo[(((size_t)bb * 16 + h) * 2048 + t + r) * 64 + d] =
                __float2bfloat16((acc[i][j][r] + bs) * 0.18033688011112042f);
        } else if (ng < 2048) {
          const int h = (ng - 1024) >> 6;
#pragma unroll
          for (int r = 0; r < 4; ++r)
            Ko[(((size_t)bb * 16 + h) * 2048 + t + r) * 64 + d] =
                __float2bfloat16(acc[i][j][r] + bs);
        } else {
          const int h = (ng - 2048) >> 6;
          short4v vv;
#pragma unroll
          for (int r = 0; r < 4; ++r) vv[r] = (short)f2b(acc[i][j][r] + bs);
          *(short4v*)&Vo[(((size_t)bb * 16 + h) * 64 + d) * 2048 + t] = vv;
        }
      } else {
#pragma unroll
        for (int r = 0; r < 4; ++r)
          Fo[(size_t)(mgb + r) * N + ng] = acc[i][j][r] + bs;
      }
    }
  }
}

// ---------------- flash attention v7: balanced dispatch + setprio + max3 ----------------
// v6 + (a) CU-balanced tile map: g=s>>3 -> tb in {15..12,8..11,7..4,0..3} so any
// stride-4 subset of g sums to 30 tiles (68 steps) -- fixes the 80-vs-56-step CU
// imbalance of monotone big-first order; (b) T5 setprio around MFMA clusters;
// (c) T17 v_max3 softmax tree.
#define T_SEQ 2048

__global__ __launch_bounds__(256) void k_attn(
    const bf16* __restrict__ Q, const bf16* __restrict__ K,
    const bf16* __restrict__ Vt, bf16* __restrict__ Y) {
  __shared__ bf16 sK[2][64 * 64];
  __shared__ bf16 sV[2][64 * 64];

  const int tid = threadIdx.x;
  const int w = tid >> 6, l = tid & 63;
  const int lg = l >> 4, li = l & 15;
  const int bid = blockIdx.x;
  const int sq = bid >> 3;
  const int bh = (bid & 7) * 8 + (sq & 7);  // all 16 tiles of a head on one XCD
  const int g = sq >> 3;                    // 0..15, dispatch order
  const int qd = g >> 2, rr = g & 3;        // balanced map: {15,8,7,0} etc per CU
  const int tb = (qd == 0) ? 15 - rr : (qd == 1) ? 8 + rr : (qd == 2) ? 7 - rr : rr;
  const int b = bh >> 4, h = bh & 15;

  const bf16* Qp = Q + (size_t)bh * (T_SEQ * 64);
  const bf16* Kp = K + (size_t)bh * (T_SEQ * 64);
  const bf16* Vp = Vt + (size_t)bh * (64 * T_SEQ);

  const int q0 = tb * 128;
  const int wq0 = q0 + w * 32;
  const int nst = (q0 + 128) >> 6;

  // Q B-frags (swapped mfma): row q = wq0+rg*16+li, d-chunk dc*32+lg*8
  short8 aq[2][2];
#pragma unroll
  for (int rg = 0; rg < 2; ++rg)
#pragma unroll
    for (int dc = 0; dc < 2; ++dc)
      aq[rg][dc] = *(const short8*)(Qp + (size_t)(wq0 + rg * 16 + li) * 64 + dc * 32 + lg * 8);

  floatx4 o[2][4];
#pragma unroll
  for (int rg = 0; rg < 2; ++rg)
#pragma unroll
    for (int f = 0; f < 4; ++f) o[rg][f] = fzero4();
  float m[2] = {-INFINITY, -INFINITY};
  float lsum[2] = {0.f, 0.f};   // partial over this lane's 16-k groups

  auto STAGE = [&](int buf, int k0) {
#pragma unroll
    for (int half = 0; half < 2; ++half) {
      const int c = half * 256 + tid;
      const int row = c >> 3, cs = c & 7;
      const int sc = cs ^ (row & 7);
      bf16* kb = &sK[buf][(half * 256 + w * 64) * 8];
      bf16* vb = &sV[buf][(half * 256 + w * 64) * 8];
      gload16(Kp + (size_t)(k0 + row) * 64 + sc * 8, kb);
      gload16(Vp + (size_t)row * T_SEQ + k0 + sc * 8, vb);
    }
  };

  int cur = 0;
  STAGE(0, 0);
  for (int t = 0; t < nst; ++t) {
    const int k0 = t << 6;
    if (t + 1 < nst) {
      STAGE(cur ^ 1, k0 + 64);                          // prefetch stays in flight
      asm volatile("s_waitcnt vmcnt(4)" ::: "memory");  // tile-t loads landed
    } else {
      asm volatile("s_waitcnt vmcnt(0)" ::: "memory");  // last tile: drain
    }
    __builtin_amdgcn_s_barrier();                       // all waves' tile-t landed
    if (k0 <= wq0 + 31) {
      // ---- swapped QK^T: s[rg][kt]: lane holds q=li(+rg*16), k=kt*16+lg*4+r ----
      floatx4 s[2][4];
      __builtin_amdgcn_s_setprio(1);
#pragma unroll
      for (int kt = 0; kt < 4; ++kt) {
        const int rowk = kt * 16 + li;
        const short8 kb0 = *(const short8*)&sK[cur][rowk * 64 + ((lg ^ (rowk & 7)) * 8)];
        const short8 kb1 = *(const short8*)&sK[cur][rowk * 64 + (((4 + lg) ^ (rowk & 7)) * 8)];
#pragma unroll
        for (int rg = 0; rg < 2; ++rg) {
          floatx4 acc = __builtin_amdgcn_mfma_f32_16x16x32_bf16(kb0, aq[rg][0], fzero4(), 0, 0, 0);
          s[rg][kt] = __builtin_amdgcn_mfma_f32_16x16x32_bf16(kb1, aq[rg][1], acc, 0, 0, 0);
        }
      }
      __builtin_amdgcn_s_setprio(0);
      // ---- causal mask (diagonal steps only) ----
      if (k0 + 63 > wq0) {
#pragma unroll
        for (int rg = 0; rg < 2; ++rg) {
          const int qg = wq0 + rg * 16 + li;
#pragma unroll
          for (int kt = 0; kt < 4; ++kt) {
            const int kgb = k0 + kt * 16 + lg * 4;
#pragma unroll
            for (int r = 0; r < 4; ++r)
              if (kgb + r > qg) s[rg][kt][r] = -1e30f;
          }
        }
      }
      // ---- row max: v_max3 tree (7 insts) + 2-hop shfl reduce ----
      float pm[2];
#pragma unroll
      for (int rg = 0; rg < 2; ++rg) {
        float t0 = max3f(s[rg][0][0], s[rg][0][1], s[rg][0][2]);
        float t1 = max3f(s[rg][0][3], s[rg][1][0], s[rg][1][1]);
        float t2 = max3f(s[rg][1][2], s[rg][1][3], s[rg][2][0]);
        float t3 = max3f(s[rg][2][1], s[rg][2][2], s[rg][2][3]);
        float t4 = max3f(s[rg][3][0], s[rg][3][1], s[rg][3][2]);
        float p = fmaxf(max3f(t0, t1, t2), max3f(t3, t4, s[rg][3][3]));
        p = fmaxf(p, __shfl_xor(p, 16));
        p = fmaxf(p, __shfl_xor(p, 32));
        pm[rg] = p;
      }
      // ---- defer-max: rescale only when max grew by > 8 (log2 units) ----
      const float need = fmaxf(pm[0] - m[0], pm[1] - m[1]);
      if (!__all(need <= 8.0f)) {
#pragma unroll
        for (int rg = 0; rg < 2; ++rg) {
          const float mn = fmaxf(m[rg], pm[rg]);
          const float a = ex2(m[rg] - mn);
          m[rg] = mn;
          lsum[rg] *= a;
          float ar[4];
#pragma unroll
          for (int r = 0; r < 4; ++r) ar[r] = __shfl(a, lg * 4 + r);
#pragma unroll
          for (int f = 0; f < 4; ++f) {
            o[rg][f][0] *= ar[0]; o[rg][f][1] *= ar[1];
            o[rg][f][2] *= ar[2]; o[rg][f][3] *= ar[3];
          }
        }
      }
      // ---- exp2 -> P stays in registers as K=16 A-frags (k = kt*16+lg*4+r) ----
      short4v pa4[2][4];
#pragma unroll
      for (int rg = 0; rg < 2; ++rg) {
#pragma unroll
        for (int kt = 0; kt < 4; ++kt) {
          const float e0 = ex2(s[rg][kt][0] - m[rg]);
          const float e1 = ex2(s[rg][kt][1] - m[rg]);
          const float e2 = ex2(s[rg][kt][2] - m[rg]);
          const float e3 = ex2(s[rg][kt][3] - m[rg]);
          lsum[rg] += (e0 + e1) + (e2 + e3);
          short4v pv;
          pv[0] = (short)f2b(e0); pv[1] = (short)f2b(e1);
          pv[2] = (short)f2b(e2); pv[3] = (short)f2b(e3);
          pa4[rg][kt] = pv;
        }
      }
      // ---- PV: o[rg][f] += P @ V via 4x mfma16 per d-block (register A-frags) ----
      __builtin_amdgcn_s_setprio(1);
#pragma unroll
      for (int f = 0; f < 4; ++f) {
        const int rowv = f * 16 + li;
        const int rx = rowv & 7;
#pragma unroll
        for (int kt = 0; kt < 4; ++kt) {
          const int cc = 2 * kt + (lg >> 1);
          const short4v vb4 = *(const short4v*)&sV[cur][rowv * 64 + (((cc ^ rx) << 3) | ((lg & 1) << 2))];
          o[0][f] = mfma16(pa4[0][kt], vb4, o[0][f]);
          o[1][f] = mfma16(pa4[1][kt], vb4, o[1][f]);
        }
      }
      __builtin_amdgcn_s_setprio(0);
    }
    __builtin_amdgcn_s_barrier();                       // all waves done reading buf[cur]
    cur ^= 1;
  }
  // ---- epilogue: finish lsum reduce, broadcast inv to o rows, write Y ----
#pragma unroll
  for (int rg = 0; rg < 2; ++rg) {
    float Ls = lsum[rg];
    Ls += __shfl_xor(Ls, 16);
    Ls += __shfl_xor(Ls, 32);
#pragma unroll
    for (int r = 0; r < 4; ++r) {
      const float inv = 1.0f / __shfl(Ls, lg * 4 + r);
      const int qg = wq0 + rg * 16 + lg * 4 + r;
      const size_t base = ((size_t)b * T_SEQ + qg) * 1024 + h * 64;
#pragma unroll
      for (int f = 0; f < 4; ++f)
        Y[base + f * 16 + li] = __float2bfloat16(o[rg][f][r] * inv);
    }
  }
}

// ---------------- launch ----------------
extern "C" void kernel_launch(void* const* d_in, const int* in_sizes, int n_in,
                              void* d_out, int out_size, void* d_ws, size_t ws_size,
                              hipStream_t stream) {
  const float* x      = (const float*)d_in[0];
  const float* W_attn = (const float*)d_in[1];
  const float* b_attn = (const float*)d_in[2];
  const float* W_proj = (const float*)d_in[3];
  const float* b_proj = (const float*)d_in[4];
  float* out = (float*)d_out;

  char* ws = (char*)d_ws;
  bf16* Wt_a = (bf16*)(ws);
  bf16* Wt_p = (bf16*)(ws + 6291456);
  bf16* Qb   = (bf16*)(ws + 8388608);
  bf16* Kb   = (bf16*)(ws + 25165824);
  bf16* Vtb  = (bf16*)(ws + 41943040);
  bf16* x_bf = (bf16*)(ws + 58720256);
  bf16* Yb   = x_bf;  // alias: x_bf dead after GEMM1

  k_cast<<<4096, 256, 0, stream>>>(x, x_bf, 8388608);
  k_transpose<<<dim3(96, 32), dim3(32, 8), 0, stream>>>(W_attn, Wt_a, 1024, 3072);
  k_transpose<<<dim3(32, 32), dim3(32, 8), 0, stream>>>(W_proj, Wt_p, 1024, 1024);
  // 1D grids, XCD-swizzled inside: GEMM1 24x64=1536 blocks, GEMM2 8x64=512.
  k_gemm<0><<<1536, 256, 0, stream>>>(x_bf, Wt_a, b_attn, Qb, Kb, Vtb,
                                      nullptr, 8192, 3072, 1024);
  k_attn<<<1024, 256, 0, stream>>>(Qb, Kb, Vtb, Yb);
  k_gemm<1><<<512, 256, 0, stream>>>(Yb, Wt_p, b_proj, nullptr, nullptr,
                                     nullptr, out, 8192, 1024, 1024);
}